// Round 1
// baseline (7260.055 us; speedup 1.0000x reference)
//
#include <hip/hip_runtime.h>
#include <hip/hip_bf16.h>

// ---------------------------------------------------------------------------
// 2-layer GCN: out = GCN2(relu(GCN1(x)))
// GCNConv: deg = segsum(ew,dst)+1 (self loop), dinv = deg^-1/2,
//          norm_e = dinv[src]*ew*dinv[dst];  out[dst] += norm_e * (xW)[src]
//          + self-loop term dinv[i]^2 * (xW)[i]  + bias
// ---------------------------------------------------------------------------

__global__ __launch_bounds__(256) void init_deg(float* deg, int N) {
    int i = blockIdx.x * 256 + threadIdx.x;
    if (i < N) deg[i] = 1.0f;  // self-loop weight
}

__global__ __launch_bounds__(256) void accum_deg(const int* __restrict__ dst,
                                                 const float* __restrict__ ew,
                                                 float* deg, int E) {
    int e = blockIdx.x * 256 + threadIdx.x;
    if (e < E) atomicAdd(&deg[dst[e]], ew[e]);
}

__global__ __launch_bounds__(256) void compute_dinv(float* deg, int N) {
    int i = blockIdx.x * 256 + threadIdx.x;
    if (i < N) deg[i] = rsqrtf(deg[i]);  // deg >= 1 always (self loop)
}

__global__ __launch_bounds__(256) void compute_norm(const int* __restrict__ src,
                                                    const int* __restrict__ dst,
                                                    const float* __restrict__ ew,
                                                    const float* __restrict__ dinv,
                                                    float* __restrict__ norm, int E) {
    int e = blockIdx.x * 256 + threadIdx.x;
    if (e < E) norm[e] = dinv[src[e]] * ew[e] * dinv[dst[e]];
}

// ---------------- fp32 tiled GEMM: C[M,N] = A[M,K] * B[K,N] ----------------
#define BM 64
#define BN 64
#define BK 16

__global__ __launch_bounds__(256) void sgemm(const float* __restrict__ A,
                                             const float* __restrict__ B,
                                             float* __restrict__ C,
                                             int M, int N, int K) {
    __shared__ float As[BK][BM + 4];  // transposed A tile, padded
    __shared__ float Bs[BK][BN];
    int tid = threadIdx.x;
    int tx = tid & 15, ty = tid >> 4;
    int bm = blockIdx.y * BM, bn = blockIdx.x * BN;

    float acc[4][4] = {};

    int arow = tid >> 2;         // 0..63
    int acol = (tid & 3) * 4;    // 0,4,8,12
    int brow = tid >> 4;         // 0..15
    int bcol = (tid & 15) * 4;   // 0..60
    const float* Aptr = A + (size_t)(bm + arow) * K;
    bool arow_ok = (bm + arow) < M;

    for (int k0 = 0; k0 < K; k0 += BK) {
#pragma unroll
        for (int j = 0; j < 4; ++j) {
            int kk = k0 + acol + j;
            float v = (arow_ok && kk < K) ? Aptr[kk] : 0.0f;
            As[acol + j][arow] = v;
        }
        {
            int kk = k0 + brow;
            float4 v = make_float4(0.f, 0.f, 0.f, 0.f);
            if (kk < K) v = *(const float4*)&B[(size_t)kk * N + bn + bcol];
            *(float4*)&Bs[brow][bcol] = v;
        }
        __syncthreads();
#pragma unroll
        for (int kk = 0; kk < BK; ++kk) {
            float4 a = *(const float4*)&As[kk][ty * 4];
            float4 b = *(const float4*)&Bs[kk][tx * 4];
            float av[4] = {a.x, a.y, a.z, a.w};
            float bv[4] = {b.x, b.y, b.z, b.w};
#pragma unroll
            for (int i = 0; i < 4; ++i)
#pragma unroll
                for (int j = 0; j < 4; ++j)
                    acc[i][j] = fmaf(av[i], bv[j], acc[i][j]);
        }
        __syncthreads();
    }
#pragma unroll
    for (int i = 0; i < 4; ++i) {
        int row = bm + ty * 4 + i;
        if (row < M) {
            float4 v = make_float4(acc[i][0], acc[i][1], acc[i][2], acc[i][3]);
            *(float4*)&C[(size_t)row * N + bn + tx * 4] = v;
        }
    }
}

// --------- init output with self-loop contribution (+optional bias) --------
template <int F>
__global__ __launch_bounds__(256) void selfloop_init(const float* __restrict__ xw,
                                                     const float* __restrict__ dinv,
                                                     const float* __restrict__ bias,
                                                     float* __restrict__ out,
                                                     int N, int useBias) {
    size_t i = (size_t)blockIdx.x * 256 + threadIdx.x;  // one float4 each
    size_t total = (size_t)N * (F / 4);
    if (i >= total) return;
    int node = (int)(i / (F / 4));
    int f4 = (int)(i % (F / 4));
    float di = dinv[node];
    float w = di * di;
    float4 v = ((const float4*)xw)[i];
    float4 o;
    o.x = w * v.x; o.y = w * v.y; o.z = w * v.z; o.w = w * v.w;
    if (useBias) {
        float4 bb = ((const float4*)bias)[f4];
        o.x += bb.x; o.y += bb.y; o.z += bb.z; o.w += bb.w;
    }
    ((float4*)out)[i] = o;
}

// ------------------- edge scatter: out[dst] += norm * in[src] --------------
__global__ __launch_bounds__(256) void scatter_f256(const int* __restrict__ src,
                                                    const int* __restrict__ dst,
                                                    const float* __restrict__ norm,
                                                    const float* __restrict__ in,
                                                    float* out, int E) {
    int e = blockIdx.x * 4 + (threadIdx.x >> 6);  // one wave (64 lanes) per edge
    if (e >= E) return;
    int lane = threadIdx.x & 63;
    int s = src[e], d = dst[e];
    float w = norm[e];
    float4 v = *(const float4*)&in[(size_t)s * 256 + lane * 4];
    float* o = &out[(size_t)d * 256 + lane * 4];
    atomicAdd(o + 0, w * v.x);
    atomicAdd(o + 1, w * v.y);
    atomicAdd(o + 2, w * v.z);
    atomicAdd(o + 3, w * v.w);
}

__global__ __launch_bounds__(256) void scatter_f64(const int* __restrict__ src,
                                                   const int* __restrict__ dst,
                                                   const float* __restrict__ norm,
                                                   const float* __restrict__ in,
                                                   float* out, int E) {
    int e = blockIdx.x * 16 + (threadIdx.x >> 4);  // 16 lanes per edge
    if (e >= E) return;
    int lane = threadIdx.x & 15;
    int s = src[e], d = dst[e];
    float w = norm[e];
    float4 v = *(const float4*)&in[(size_t)s * 64 + lane * 4];
    float* o = &out[(size_t)d * 64 + lane * 4];
    atomicAdd(o + 0, w * v.x);
    atomicAdd(o + 1, w * v.y);
    atomicAdd(o + 2, w * v.z);
    atomicAdd(o + 3, w * v.w);
}

// ------------------------ bias + relu (in place) ---------------------------
template <int F>
__global__ __launch_bounds__(256) void bias_relu(float* __restrict__ h,
                                                 const float* __restrict__ bias,
                                                 int N) {
    size_t i = (size_t)blockIdx.x * 256 + threadIdx.x;
    size_t total = (size_t)N * (F / 4);
    if (i >= total) return;
    int f4 = (int)(i % (F / 4));
    float4 v = ((float4*)h)[i];
    float4 bb = ((const float4*)bias)[f4];
    v.x = fmaxf(v.x + bb.x, 0.f);
    v.y = fmaxf(v.y + bb.y, 0.f);
    v.z = fmaxf(v.z + bb.z, 0.f);
    v.w = fmaxf(v.w + bb.w, 0.f);
    ((float4*)h)[i] = v;
}

extern "C" void kernel_launch(void* const* d_in, const int* in_sizes, int n_in,
                              void* d_out, int out_size, void* d_ws, size_t ws_size,
                              hipStream_t stream) {
    const float* x  = (const float*)d_in[0];
    const int*   ei = (const int*)d_in[1];
    const float* ew = (const float*)d_in[2];
    const float* W1 = (const float*)d_in[3];
    const float* b1 = (const float*)d_in[4];
    const float* W2 = (const float*)d_in[5];
    const float* b2 = (const float*)d_in[6];
    float* out = (float*)d_out;

    const int H    = in_sizes[4];            // 256
    const int Fout = in_sizes[6];            // 64
    const int Fin  = in_sizes[3] / H;        // 394
    const int N    = in_sizes[0] / Fin;      // 100000
    const int E    = in_sizes[2];            // 1600000

    const int* src = ei;
    const int* dst = ei + E;

    // workspace layout (floats)
    float* ws    = (float*)d_ws;
    float* dinv  = ws;                        // N
    float* norm  = dinv + N;                  // E
    float* bufA  = norm + E;                  // N*H  (xw1, later xw2)
    float* bufB  = bufA + (size_t)N * H;      // N*H  (h)

    // 1. degrees (incl. self-loop) -> dinv
    init_deg<<<(N + 255) / 256, 256, 0, stream>>>(dinv, N);
    accum_deg<<<(E + 255) / 256, 256, 0, stream>>>(dst, ew, dinv, E);
    compute_dinv<<<(N + 255) / 256, 256, 0, stream>>>(dinv, N);
    compute_norm<<<(E + 255) / 256, 256, 0, stream>>>(src, dst, ew, dinv, norm, E);

    // 2. xw1 = x @ W1   [N,394]@[394,256]
    {
        dim3 grid(H / BN, (N + BM - 1) / BM);
        sgemm<<<grid, 256, 0, stream>>>(x, W1, bufA, N, H, Fin);
    }

    // 3. h = selfloop + scatter(edges), then relu(h + b1)
    selfloop_init<256><<<(N * 64 + 255) / 256, 256, 0, stream>>>(bufA, dinv, b1, bufB, N, 0);
    scatter_f256<<<(E + 3) / 4, 256, 0, stream>>>(src, dst, norm, bufA, bufB, E);
    bias_relu<256><<<(N * 64 + 255) / 256, 256, 0, stream>>>(bufB, b1, N);

    // 4. xw2 = h @ W2   [N,256]@[256,64]
    {
        dim3 grid(Fout / BN, (N + BM - 1) / BM);
        sgemm<<<grid, 256, 0, stream>>>(bufB, W2, bufA, N, Fout, H);
    }

    // 5. out = selfloop + b2 + scatter(edges)
    selfloop_init<64><<<(N * 16 + 255) / 256, 256, 0, stream>>>(bufA, dinv, b2, out, N, 1);
    scatter_f64<<<(E + 15) / 16, 256, 0, stream>>>(src, dst, norm, bufA, out, E);
}

// Round 2
// 1063.646 us; speedup vs baseline: 6.8256x; 6.8256x over previous
//
#include <hip/hip_runtime.h>
#include <hip/hip_bf16.h>

// ---------------------------------------------------------------------------
// 2-layer GCN, CSR-gather formulation (no atomics in aggregation):
//   deg = segsum(ew,dst)+1 ; dinv = deg^-1/2
//   CSR sort edges by dst; val = dinv[src]*ew*dinv[dst]
//   out[d] = sum_p val[p]*xw[col[p]]  +  dinv[d]^2*xw[d]  + bias (; relu)
// ---------------------------------------------------------------------------

__global__ __launch_bounds__(256) void init_node(float* deg, int* counts, int* fillc, int N) {
    int i = blockIdx.x * 256 + threadIdx.x;
    if (i < N) { deg[i] = 1.0f; counts[i] = 0; fillc[i] = 0; }
}

__global__ __launch_bounds__(256) void accum_deg_hist(const int* __restrict__ dst,
                                                      const float* __restrict__ ew,
                                                      float* deg, int* counts, int E) {
    int e = blockIdx.x * 256 + threadIdx.x;
    if (e < E) {
        int d = dst[e];
        atomicAdd(&deg[d], ew[e]);
        atomicAdd(&counts[d], 1);
    }
}

__global__ __launch_bounds__(256) void compute_dinv(float* deg, int N) {
    int i = blockIdx.x * 256 + threadIdx.x;
    if (i < N) deg[i] = rsqrtf(deg[i]);
}

// ---- 3-kernel exclusive scan of counts[N] -> rowptr[N] (+rowptr[N]=E) -----
#define SCAN_TILE 2048  // 256 threads x 8

__global__ __launch_bounds__(256) void scan1(const int* __restrict__ counts,
                                             int* __restrict__ rowptr,
                                             int* __restrict__ bsums, int N) {
    __shared__ int tmp[256];
    int t = threadIdx.x;
    int base = blockIdx.x * SCAN_TILE + t * 8;
    int v[8], s = 0;
#pragma unroll
    for (int j = 0; j < 8; ++j) { v[j] = (base + j < N) ? counts[base + j] : 0; s += v[j]; }
    tmp[t] = s;
    __syncthreads();
#pragma unroll
    for (int off = 1; off < 256; off <<= 1) {
        int u = (t >= off) ? tmp[t - off] : 0;
        __syncthreads();
        tmp[t] += u;
        __syncthreads();
    }
    int run = tmp[t] - s;  // exclusive prefix of this thread
#pragma unroll
    for (int j = 0; j < 8; ++j) {
        if (base + j < N) rowptr[base + j] = run;
        run += v[j];
    }
    if (t == 255) bsums[blockIdx.x] = tmp[255];
}

__global__ __launch_bounds__(256) void scan2(int* bsums, int* rowptr, int NB, int N, int E) {
    __shared__ int tmp[256];
    int t = threadIdx.x;
    int v = (t < NB) ? bsums[t] : 0;
    tmp[t] = v;
    __syncthreads();
#pragma unroll
    for (int off = 1; off < 256; off <<= 1) {
        int u = (t >= off) ? tmp[t - off] : 0;
        __syncthreads();
        tmp[t] += u;
        __syncthreads();
    }
    if (t < NB) bsums[t] = tmp[t] - v;  // exclusive
    if (t == 0) rowptr[N] = E;
}

__global__ __launch_bounds__(256) void scan3(int* rowptr, const int* __restrict__ bsums, int N) {
    int base = blockIdx.x * SCAN_TILE + threadIdx.x * 8;
    int off = bsums[blockIdx.x];
#pragma unroll
    for (int j = 0; j < 8; ++j)
        if (base + j < N) rowptr[base + j] += off;
}

// ---- fill CSR: col/val sorted by dst --------------------------------------
__global__ __launch_bounds__(256) void fill_csr(const int* __restrict__ src,
                                                const int* __restrict__ dst,
                                                const float* __restrict__ ew,
                                                const float* __restrict__ dinv,
                                                const int* __restrict__ rowptr,
                                                int* __restrict__ fillc,
                                                int* __restrict__ col,
                                                float* __restrict__ val, int E) {
    int e = blockIdx.x * 256 + threadIdx.x;
    if (e < E) {
        int d = dst[e], s = src[e];
        int pos = rowptr[d] + atomicAdd(&fillc[d], 1);
        col[pos] = s;
        val[pos] = dinv[s] * ew[e] * dinv[d];
    }
}

// ---------------- fp32 tiled GEMM: C[M,N] = A[M,K] * B[K,N] ----------------
#define BM 64
#define BN 64
#define BK 16

__global__ __launch_bounds__(256) void sgemm(const float* __restrict__ A,
                                             const float* __restrict__ B,
                                             float* __restrict__ C,
                                             int M, int N, int K) {
    __shared__ float As[BK][BM + 4];
    __shared__ float Bs[BK][BN];
    int tid = threadIdx.x;
    int tx = tid & 15, ty = tid >> 4;
    int bm = blockIdx.y * BM, bn = blockIdx.x * BN;

    float acc[4][4] = {};

    int arow = tid >> 2;
    int acol = (tid & 3) * 4;
    int brow = tid >> 4;
    int bcol = (tid & 15) * 4;
    const float* Aptr = A + (size_t)(bm + arow) * K;
    bool arow_ok = (bm + arow) < M;

    for (int k0 = 0; k0 < K; k0 += BK) {
#pragma unroll
        for (int j = 0; j < 4; ++j) {
            int kk = k0 + acol + j;
            As[acol + j][arow] = (arow_ok && kk < K) ? Aptr[kk] : 0.0f;
        }
        {
            int kk = k0 + brow;
            float4 v = make_float4(0.f, 0.f, 0.f, 0.f);
            if (kk < K) v = *(const float4*)&B[(size_t)kk * N + bn + bcol];
            *(float4*)&Bs[brow][bcol] = v;
        }
        __syncthreads();
#pragma unroll
        for (int kk = 0; kk < BK; ++kk) {
            float4 a = *(const float4*)&As[kk][ty * 4];
            float4 b = *(const float4*)&Bs[kk][tx * 4];
            float av[4] = {a.x, a.y, a.z, a.w};
            float bv[4] = {b.x, b.y, b.z, b.w};
#pragma unroll
            for (int i = 0; i < 4; ++i)
#pragma unroll
                for (int j = 0; j < 4; ++j)
                    acc[i][j] = fmaf(av[i], bv[j], acc[i][j]);
        }
        __syncthreads();
    }
#pragma unroll
    for (int i = 0; i < 4; ++i) {
        int row = bm + ty * 4 + i;
        if (row < M)
            *(float4*)&C[(size_t)row * N + bn + tx * 4] =
                make_float4(acc[i][0], acc[i][1], acc[i][2], acc[i][3]);
    }
}

// ---- gather aggregation: out[d] = selfloop + sum_{p} val[p]*xw[col[p]] ----
// LPN lanes cooperate on one node's F features (F = LPN*4).
template <int F, int LPN, int RELU>
__global__ __launch_bounds__(256) void gather(const int* __restrict__ rowptr,
                                              const int* __restrict__ col,
                                              const float* __restrict__ val,
                                              const float* __restrict__ xw,
                                              const float* __restrict__ dinv,
                                              const float* __restrict__ bias,
                                              float* __restrict__ out, int N) {
    const int NPB = 256 / LPN;  // nodes per block
    int d = blockIdx.x * NPB + threadIdx.x / LPN;
    if (d >= N) return;
    int lane = threadIdx.x % LPN;

    float di = dinv[d];
    float w = di * di;
    float4 v = *(const float4*)&xw[(size_t)d * F + lane * 4];
    float a0 = w * v.x, a1 = w * v.y, a2 = w * v.z, a3 = w * v.w;

    int p0 = rowptr[d], p1 = rowptr[d + 1];
    for (int p = p0; p < p1; ++p) {
        int s = col[p];
        float wv = val[p];
        float4 u = *(const float4*)&xw[(size_t)s * F + lane * 4];
        a0 = fmaf(wv, u.x, a0);
        a1 = fmaf(wv, u.y, a1);
        a2 = fmaf(wv, u.z, a2);
        a3 = fmaf(wv, u.w, a3);
    }
    float4 bb = *(const float4*)&bias[lane * 4];
    a0 += bb.x; a1 += bb.y; a2 += bb.z; a3 += bb.w;
    if (RELU) {
        a0 = fmaxf(a0, 0.f); a1 = fmaxf(a1, 0.f);
        a2 = fmaxf(a2, 0.f); a3 = fmaxf(a3, 0.f);
    }
    *(float4*)&out[(size_t)d * F + lane * 4] = make_float4(a0, a1, a2, a3);
}

extern "C" void kernel_launch(void* const* d_in, const int* in_sizes, int n_in,
                              void* d_out, int out_size, void* d_ws, size_t ws_size,
                              hipStream_t stream) {
    const float* x  = (const float*)d_in[0];
    const int*   ei = (const int*)d_in[1];
    const float* ew = (const float*)d_in[2];
    const float* W1 = (const float*)d_in[3];
    const float* b1 = (const float*)d_in[4];
    const float* W2 = (const float*)d_in[5];
    const float* b2 = (const float*)d_in[6];
    float* out = (float*)d_out;

    const int H    = in_sizes[4];            // 256
    const int Fout = in_sizes[6];            // 64
    const int Fin  = in_sizes[3] / H;        // 394
    const int N    = in_sizes[0] / Fin;      // 100000
    const int E    = in_sizes[2];            // 1600000

    const int* src = ei;
    const int* dst = ei + E;

    // workspace layout
    float* ws     = (float*)d_ws;
    float* dinv   = ws;                          // N floats (deg -> dinv)
    int*   counts = (int*)(dinv + N);            // N
    int*   fillc  = counts + N;                  // N
    int*   rowptr = fillc + N;                   // N+1
    int*   bsums  = rowptr + N + 1;              // 256 (padding)
    int*   col    = bsums + 256;                 // E
    float* val    = (float*)(col + E);           // E
    float* bufA   = val + E;                     // N*H
    float* bufB   = bufA + (size_t)N * H;        // N*H

    const int NB = (N + SCAN_TILE - 1) / SCAN_TILE;  // 49

    // 1. degrees + histogram
    init_node<<<(N + 255) / 256, 256, 0, stream>>>(dinv, counts, fillc, N);
    accum_deg_hist<<<(E + 255) / 256, 256, 0, stream>>>(dst, ew, dinv, counts, E);
    compute_dinv<<<(N + 255) / 256, 256, 0, stream>>>(dinv, N);

    // 2. CSR build: exclusive scan + fill
    scan1<<<NB, 256, 0, stream>>>(counts, rowptr, bsums, N);
    scan2<<<1, 256, 0, stream>>>(bsums, rowptr, NB, N, E);
    scan3<<<NB, 256, 0, stream>>>(rowptr, bsums, N);
    fill_csr<<<(E + 255) / 256, 256, 0, stream>>>(src, dst, ew, dinv, rowptr, fillc, col, val, E);

    // 3. xw1 = x @ W1   [N,394]@[394,256]
    {
        dim3 grid(H / BN, (N + BM - 1) / BM);
        sgemm<<<grid, 256, 0, stream>>>(x, W1, bufA, N, H, Fin);
    }

    // 4. h = gather + bias + relu
    gather<256, 64, 1><<<(N + 3) / 4, 256, 0, stream>>>(rowptr, col, val, bufA, dinv, b1, bufB, N);

    // 5. xw2 = h @ W2   [N,256]@[256,64]
    {
        dim3 grid(Fout / BN, (N + BM - 1) / BM);
        sgemm<<<grid, 256, 0, stream>>>(bufB, W2, bufA, N, Fout, H);
    }

    // 6. out = gather + bias
    gather<64, 16, 0><<<(N + 15) / 16, 256, 0, stream>>>(rowptr, col, val, bufA, dinv, b2, out, N);
}

// Round 4
// 923.786 us; speedup vs baseline: 7.8590x; 1.1514x over previous
//
#include <hip/hip_runtime.h>
#include <hip/hip_bf16.h>

// ---------------------------------------------------------------------------
// 2-layer GCN, CSR-gather aggregation + split-bf16 MFMA GEMMs.
//   fp32 GEMM via hi/lo bf16 split: acc += Ahi*Bhi + Ahi*Blo + Alo*Bhi
// ---------------------------------------------------------------------------

typedef __bf16 bf16x8 __attribute__((ext_vector_type(8)));
typedef float f32x4 __attribute__((ext_vector_type(4)));

__device__ inline ushort f2bf_hi(float f) {
    uint u = __float_as_uint(f);
    return (ushort)((u + 0x7fffu + ((u >> 16) & 1u)) >> 16);  // RNE
}
__device__ inline float bf2f(ushort h) { return __uint_as_float(((uint)h) << 16); }

// ------------------------- graph preprocessing -----------------------------

__global__ __launch_bounds__(256) void init_node(float* deg, int* counts, int* fillc, int N) {
    int i = blockIdx.x * 256 + threadIdx.x;
    if (i < N) { deg[i] = 1.0f; counts[i] = 0; fillc[i] = 0; }
}

__global__ __launch_bounds__(256) void accum_deg_hist(const int* __restrict__ dst,
                                                      const float* __restrict__ ew,
                                                      float* deg, int* counts, int E) {
    int e = blockIdx.x * 256 + threadIdx.x;
    if (e < E) {
        int d = dst[e];
        atomicAdd(&deg[d], ew[e]);
        atomicAdd(&counts[d], 1);
    }
}

__global__ __launch_bounds__(256) void compute_dinv(float* deg, int N) {
    int i = blockIdx.x * 256 + threadIdx.x;
    if (i < N) deg[i] = rsqrtf(deg[i]);
}

#define SCAN_TILE 2048

__global__ __launch_bounds__(256) void scan1(const int* __restrict__ counts,
                                             int* __restrict__ rowptr,
                                             int* __restrict__ bsums, int N) {
    __shared__ int tmp[256];
    int t = threadIdx.x;
    int base = blockIdx.x * SCAN_TILE + t * 8;
    int v[8], s = 0;
#pragma unroll
    for (int j = 0; j < 8; ++j) { v[j] = (base + j < N) ? counts[base + j] : 0; s += v[j]; }
    tmp[t] = s;
    __syncthreads();
#pragma unroll
    for (int off = 1; off < 256; off <<= 1) {
        int u = (t >= off) ? tmp[t - off] : 0;
        __syncthreads();
        tmp[t] += u;
        __syncthreads();
    }
    int run = tmp[t] - s;
#pragma unroll
    for (int j = 0; j < 8; ++j) {
        if (base + j < N) rowptr[base + j] = run;
        run += v[j];
    }
    if (t == 255) bsums[blockIdx.x] = tmp[255];
}

__global__ __launch_bounds__(256) void scan2(int* bsums, int* rowptr, int NB, int N, int E) {
    __shared__ int tmp[256];
    int t = threadIdx.x;
    int v = (t < NB) ? bsums[t] : 0;
    tmp[t] = v;
    __syncthreads();
#pragma unroll
    for (int off = 1; off < 256; off <<= 1) {
        int u = (t >= off) ? tmp[t - off] : 0;
        __syncthreads();
        tmp[t] += u;
        __syncthreads();
    }
    if (t < NB) bsums[t] = tmp[t] - v;
    if (t == 0) rowptr[N] = E;
}

__global__ __launch_bounds__(256) void scan3(int* rowptr, const int* __restrict__ bsums, int N) {
    int base = blockIdx.x * SCAN_TILE + threadIdx.x * 8;
    int off = bsums[blockIdx.x];
#pragma unroll
    for (int j = 0; j < 8; ++j)
        if (base + j < N) rowptr[base + j] += off;
}

__global__ __launch_bounds__(256) void fill_csr(const int* __restrict__ src,
                                                const int* __restrict__ dst,
                                                const float* __restrict__ ew,
                                                const float* __restrict__ dinv,
                                                const int* __restrict__ rowptr,
                                                int* __restrict__ fillc,
                                                int* __restrict__ col,
                                                float* __restrict__ val, int E) {
    int e = blockIdx.x * 256 + threadIdx.x;
    if (e < E) {
        int d = dst[e], s = src[e];
        int pos = rowptr[d] + atomicAdd(&fillc[d], 1);
        col[pos] = s;
        val[pos] = dinv[s] * ew[e] * dinv[d];
    }
}

// --------- split W[K][N] into bf16 hi/lo planes, transposed [N][Kpad] ------
__global__ __launch_bounds__(256) void split_w(const float* __restrict__ W,
                                               ushort* __restrict__ WT,
                                               int K, int N, int Kpad) {
    int idx = blockIdx.x * 256 + threadIdx.x;
    int total = N * Kpad;
    if (idx >= total) return;
    int n = idx / Kpad, k = idx % Kpad;
    float v = (k < K) ? W[(size_t)k * N + n] : 0.0f;
    ushort hi = f2bf_hi(v);
    ushort lo = f2bf_hi(v - bf2f(hi));
    WT[idx] = hi;
    WT[total + idx] = lo;
}

// ---------------- split-bf16 MFMA GEMM: C[M,BN] = A[M,K] @ W[K,BN] ---------
// A fp32 row-major (converted to hi/lo bf16 during LDS staging).
// WT: two bf16 planes (hi, lo) of [BN][Kpad] (transposed W, zero-padded K).
#define LDK 40  // 32 + 8 pad: 80B rows, 16B-aligned, 8-bank cycle

template <int BM, int BN, int WARPS_M, int WARPS_N, int NT>
__global__ __launch_bounds__(NT) void mfma_gemm(const float* __restrict__ A,
                                                const ushort* __restrict__ WT,
                                                float* __restrict__ C,
                                                int M, int K, int Kpad) {
    const int WM = BM / WARPS_M, WN = BN / WARPS_N;
    const int FM = WM / 16, FN = WN / 16;
    __shared__ __align__(16) ushort As[2][BM][LDK];
    __shared__ __align__(16) ushort Bs[2][BN][LDK];

    int tid = threadIdx.x;
    int lane = tid & 63;
    int w = tid >> 6;
    int wr = w / WARPS_N, wc = w % WARPS_N;
    int bm = blockIdx.y * BM;

    int lrow = lane & 15;       // M-row (A) / N-col (B) within fragment
    int lk = (lane >> 4) * 8;   // k offset within the 32-slice

    f32x4 acc[FM][FN];
#pragma unroll
    for (int i = 0; i < FM; ++i)
#pragma unroll
        for (int j = 0; j < FN; ++j) acc[i][j] = (f32x4){0.f, 0.f, 0.f, 0.f};

    const int nsteps = Kpad / 32;
    const int A2PT = (BM * 16) / NT;   // float2 loads per thread for A tile
    const int BCH = BN * 2 * 4;        // 16B chunks: rows x planes x 4

    for (int s = 0; s < nsteps; ++s) {
        int k0 = s * 32;
        __syncthreads();  // previous compute done before overwrite
        // ---- stage A: fp32 -> hi/lo bf16 ----
#pragma unroll
        for (int i = 0; i < A2PT; ++i) {
            int e2 = tid + i * NT;          // over BM*16 float2
            int r = e2 >> 4, kc2 = e2 & 15;
            int gr = bm + r;
            int gk = k0 + kc2 * 2;
            float v0 = 0.f, v1 = 0.f;
            if (gr < M) {
                const float* p = A + (size_t)gr * K + gk;
                if (gk + 1 < K) { float2 t2 = *(const float2*)p; v0 = t2.x; v1 = t2.y; }
                else if (gk < K) { v0 = *p; }
            }
            ushort h0 = f2bf_hi(v0), h1 = f2bf_hi(v1);
            ushort l0 = f2bf_hi(v0 - bf2f(h0)), l1 = f2bf_hi(v1 - bf2f(h1));
            *(ushort2*)&As[0][r][kc2 * 2] = make_ushort2(h0, h1);
            *(ushort2*)&As[1][r][kc2 * 2] = make_ushort2(l0, l1);
        }
        // ---- stage B: bf16 planes, 4x16B chunks per 32-wide row ----
        for (int c = tid; c < BCH; c += NT) {
            int pl = (c >= BN * 4) ? 1 : 0;
            int cc = c - pl * BN * 4;
            int n = cc >> 2, kh = cc & 3;   // kh: which 8-ushort chunk of 32
            const ushort* srcp = WT + (size_t)pl * BN * Kpad + (size_t)n * Kpad + k0 + kh * 8;
            *(ulonglong2*)&Bs[pl][n][kh * 8] = *(const ulonglong2*)srcp;
        }
        __syncthreads();
        // ---- MFMA ----
        bf16x8 af[FM][2], bfr[FN][2];
#pragma unroll
        for (int m = 0; m < FM; ++m) {
            af[m][0] = *(const bf16x8*)&As[0][wr * WM + m * 16 + lrow][lk];
            af[m][1] = *(const bf16x8*)&As[1][wr * WM + m * 16 + lrow][lk];
        }
#pragma unroll
        for (int n = 0; n < FN; ++n) {
            bfr[n][0] = *(const bf16x8*)&Bs[0][wc * WN + n * 16 + lrow][lk];
            bfr[n][1] = *(const bf16x8*)&Bs[1][wc * WN + n * 16 + lrow][lk];
        }
#pragma unroll
        for (int m = 0; m < FM; ++m)
#pragma unroll
            for (int n = 0; n < FN; ++n) {
                acc[m][n] = __builtin_amdgcn_mfma_f32_16x16x32_bf16(af[m][0], bfr[n][0], acc[m][n], 0, 0, 0);
                acc[m][n] = __builtin_amdgcn_mfma_f32_16x16x32_bf16(af[m][0], bfr[n][1], acc[m][n], 0, 0, 0);
                acc[m][n] = __builtin_amdgcn_mfma_f32_16x16x32_bf16(af[m][1], bfr[n][0], acc[m][n], 0, 0, 0);
            }
    }
    // ---- epilogue: C/D layout col=lane&15, row=(lane>>4)*4+i ----
#pragma unroll
    for (int m = 0; m < FM; ++m) {
        int rb = bm + wr * WM + m * 16 + (lane >> 4) * 4;
#pragma unroll
        for (int n = 0; n < FN; ++n) {
            int cb = wc * WN + n * 16 + (lane & 15);
#pragma unroll
            for (int i = 0; i < 4; ++i) {
                int r = rb + i;
                if (r < M) C[(size_t)r * BN + cb] = acc[m][n][i];
            }
        }
    }
}

// ---- gather aggregation: out[d] = selfloop + sum_{p} val[p]*xw[col[p]] ----
template <int F, int LPN, int RELU>
__global__ __launch_bounds__(256) void gather(const int* __restrict__ rowptr,
                                              const int* __restrict__ col,
                                              const float* __restrict__ val,
                                              const float* __restrict__ xw,
                                              const float* __restrict__ dinv,
                                              const float* __restrict__ bias,
                                              float* __restrict__ out, int N) {
    const int NPB = 256 / LPN;
    int d = blockIdx.x * NPB + threadIdx.x / LPN;
    if (d >= N) return;
    int lane = threadIdx.x % LPN;

    float di = dinv[d];
    float w = di * di;
    float4 v = *(const float4*)&xw[(size_t)d * F + lane * 4];
    float a0 = w * v.x, a1 = w * v.y, a2 = w * v.z, a3 = w * v.w;

    int p0 = rowptr[d], p1 = rowptr[d + 1];
    for (int p = p0; p < p1; ++p) {
        int s = col[p];
        float wv = val[p];
        float4 u = *(const float4*)&xw[(size_t)s * F + lane * 4];
        a0 = fmaf(wv, u.x, a0);
        a1 = fmaf(wv, u.y, a1);
        a2 = fmaf(wv, u.z, a2);
        a3 = fmaf(wv, u.w, a3);
    }
    float4 bb = *(const float4*)&bias[lane * 4];
    a0 += bb.x; a1 += bb.y; a2 += bb.z; a3 += bb.w;
    if (RELU) {
        a0 = fmaxf(a0, 0.f); a1 = fmaxf(a1, 0.f);
        a2 = fmaxf(a2, 0.f); a3 = fmaxf(a3, 0.f);
    }
    *(float4*)&out[(size_t)d * F + lane * 4] = make_float4(a0, a1, a2, a3);
}

extern "C" void kernel_launch(void* const* d_in, const int* in_sizes, int n_in,
                              void* d_out, int out_size, void* d_ws, size_t ws_size,
                              hipStream_t stream) {
    const float* x  = (const float*)d_in[0];
    const int*   ei = (const int*)d_in[1];
    const float* ew = (const float*)d_in[2];
    const float* W1 = (const float*)d_in[3];
    const float* b1 = (const float*)d_in[4];
    const float* W2 = (const float*)d_in[5];
    const float* b2 = (const float*)d_in[6];
    float* out = (float*)d_out;

    const int H    = in_sizes[4];            // 256
    const int Fout = in_sizes[6];            // 64
    const int Fin  = in_sizes[3] / H;        // 394
    const int N    = in_sizes[0] / Fin;      // 100000
    const int E    = in_sizes[2];            // 1600000

    const int Kpad1 = (Fin + 31) / 32 * 32;  // 416
    const int Kpad2 = (H + 31) / 32 * 32;    // 256

    const int* src = ei;
    const int* dst = ei + E;

    // workspace layout
    float* ws     = (float*)d_ws;
    float* dinv   = ws;                          // N
    int*   counts = (int*)(dinv + N);            // N
    int*   fillc  = counts + N;                  // N
    int*   rowptr = fillc + N;                   // N+1
    int*   bsums  = rowptr + N + 1;              // 256
    int*   col    = bsums + 256;                 // E
    float* val    = (float*)(col + E);           // E
    float* bufA   = val + E;                     // N*H
    float* bufB   = bufA + (size_t)N * H;        // N*H
    ushort* wt1   = (ushort*)(bufB + (size_t)N * H);  // 2*H*Kpad1
    ushort* wt2   = wt1 + 2 * H * Kpad1;              // 2*Fout*Kpad2

    const int NB = (N + SCAN_TILE - 1) / SCAN_TILE;

    // 1. degrees + histogram + dinv
    init_node<<<(N + 255) / 256, 256, 0, stream>>>(dinv, counts, fillc, N);
    accum_deg_hist<<<(E + 255) / 256, 256, 0, stream>>>(dst, ew, dinv, counts, E);
    compute_dinv<<<(N + 255) / 256, 256, 0, stream>>>(dinv, N);

    // 2. CSR build
    scan1<<<NB, 256, 0, stream>>>(counts, rowptr, bsums, N);
    scan2<<<1, 256, 0, stream>>>(bsums, rowptr, NB, N, E);
    scan3<<<NB, 256, 0, stream>>>(rowptr, bsums, N);
    fill_csr<<<(E + 255) / 256, 256, 0, stream>>>(src, dst, ew, dinv, rowptr, fillc, col, val, E);

    // 3. weight split (hi/lo bf16, transposed)
    split_w<<<(H * Kpad1 + 255) / 256, 256, 0, stream>>>(W1, wt1, Fin, H, Kpad1);
    split_w<<<(Fout * Kpad2 + 255) / 256, 256, 0, stream>>>(W2, wt2, H, Fout, Kpad2);

    // 4. xw1 = x @ W1   [N,394]@[394,256]
    {
        dim3 grid(1, (N + 127) / 128);
        mfma_gemm<128, 256, 2, 4, 512><<<grid, 512, 0, stream>>>(x, wt1, bufA, N, Fin, Kpad1);
    }

    // 5. h = gather + bias + relu
    gather<256, 64, 1><<<(N + 3) / 4, 256, 0, stream>>>(rowptr, col, val, bufA, dinv, b1, bufB, N);

    // 6. xw2 = h @ W2   [N,256]@[256,64]
    {
        dim3 grid(1, (N + 127) / 128);
        mfma_gemm<128, 64, 2, 2, 256><<<grid, 256, 0, stream>>>(bufB, wt2, bufA, N, H, Kpad2);
    }

    // 7. out = gather + bias
    gather<64, 16, 0><<<(N + 15) / 16, 256, 0, stream>>>(rowptr, col, val, bufA, dinv, b2, out, N);
}

// Round 5
// 911.800 us; speedup vs baseline: 7.9623x; 1.0131x over previous
//
#include <hip/hip_runtime.h>
#include <hip/hip_bf16.h>

// ---------------------------------------------------------------------------
// 2-layer GCN, CSR-gather aggregation + split-bf16 MFMA GEMMs.
//   fp32 GEMM via hi/lo bf16 split: acc += Ahi*Bhi + Ahi*Blo + Alo*Bhi
// ---------------------------------------------------------------------------

typedef __bf16 bf16x8 __attribute__((ext_vector_type(8)));
typedef float f32x4 __attribute__((ext_vector_type(4)));

__device__ inline ushort f2bf_hi(float f) {
    uint u = __float_as_uint(f);
    return (ushort)((u + 0x7fffu + ((u >> 16) & 1u)) >> 16);  // RNE
}
__device__ inline float bf2f(ushort h) { return __uint_as_float(((uint)h) << 16); }

// bijective 16B-slot swizzle within a 16-row x 64B LDS subtile
#define SW(row, slot) ((slot) ^ ((row) & 3) ^ (((row) >> 2) & 3))

// ------------------------- graph preprocessing -----------------------------

__global__ __launch_bounds__(256) void init_node(float* deg, int* counts, int* fillc, int N) {
    int i = blockIdx.x * 256 + threadIdx.x;
    if (i < N) { deg[i] = 1.0f; counts[i] = 0; fillc[i] = 0; }
}

__global__ __launch_bounds__(256) void accum_deg_hist(const int* __restrict__ dst,
                                                      const float* __restrict__ ew,
                                                      float* deg, int* counts, int E) {
    int e = blockIdx.x * 256 + threadIdx.x;
    if (e < E) {
        int d = dst[e];
        atomicAdd(&deg[d], ew[e]);
        atomicAdd(&counts[d], 1);
    }
}

__global__ __launch_bounds__(256) void compute_dinv(float* deg, int N) {
    int i = blockIdx.x * 256 + threadIdx.x;
    if (i < N) deg[i] = rsqrtf(deg[i]);
}

#define SCAN_TILE 2048

__global__ __launch_bounds__(256) void scan1(const int* __restrict__ counts,
                                             int* __restrict__ rowptr,
                                             int* __restrict__ bsums, int N) {
    __shared__ int tmp[256];
    int t = threadIdx.x;
    int base = blockIdx.x * SCAN_TILE + t * 8;
    int v[8], s = 0;
#pragma unroll
    for (int j = 0; j < 8; ++j) { v[j] = (base + j < N) ? counts[base + j] : 0; s += v[j]; }
    tmp[t] = s;
    __syncthreads();
#pragma unroll
    for (int off = 1; off < 256; off <<= 1) {
        int u = (t >= off) ? tmp[t - off] : 0;
        __syncthreads();
        tmp[t] += u;
        __syncthreads();
    }
    int run = tmp[t] - s;
#pragma unroll
    for (int j = 0; j < 8; ++j) {
        if (base + j < N) rowptr[base + j] = run;
        run += v[j];
    }
    if (t == 255) bsums[blockIdx.x] = tmp[255];
}

__global__ __launch_bounds__(256) void scan2(int* bsums, int* rowptr, int NB, int N, int E) {
    __shared__ int tmp[256];
    int t = threadIdx.x;
    int v = (t < NB) ? bsums[t] : 0;
    tmp[t] = v;
    __syncthreads();
#pragma unroll
    for (int off = 1; off < 256; off <<= 1) {
        int u = (t >= off) ? tmp[t - off] : 0;
        __syncthreads();
        tmp[t] += u;
        __syncthreads();
    }
    if (t < NB) bsums[t] = tmp[t] - v;
    if (t == 0) rowptr[N] = E;
}

__global__ __launch_bounds__(256) void scan3(int* rowptr, const int* __restrict__ bsums, int N) {
    int base = blockIdx.x * SCAN_TILE + threadIdx.x * 8;
    int off = bsums[blockIdx.x];
#pragma unroll
    for (int j = 0; j < 8; ++j)
        if (base + j < N) rowptr[base + j] += off;
}

__global__ __launch_bounds__(256) void fill_csr(const int* __restrict__ src,
                                                const int* __restrict__ dst,
                                                const float* __restrict__ ew,
                                                const float* __restrict__ dinv,
                                                const int* __restrict__ rowptr,
                                                int* __restrict__ fillc,
                                                int* __restrict__ col,
                                                float* __restrict__ val, int E) {
    int e = blockIdx.x * 256 + threadIdx.x;
    if (e < E) {
        int d = dst[e], s = src[e];
        int pos = rowptr[d] + atomicAdd(&fillc[d], 1);
        col[pos] = s;
        val[pos] = dinv[s] * ew[e] * dinv[d];
    }
}

// --------- split W[K][N] into bf16 hi/lo planes, transposed [N][Kpad] ------
__global__ __launch_bounds__(256) void split_w(const float* __restrict__ W,
                                               ushort* __restrict__ WT,
                                               int K, int N, int Kpad) {
    int idx = blockIdx.x * 256 + threadIdx.x;
    int total = N * Kpad;
    if (idx >= total) return;
    int n = idx / Kpad, k = idx % Kpad;
    float v = (k < K) ? W[(size_t)k * N + n] : 0.0f;
    ushort hi = f2bf_hi(v);
    ushort lo = f2bf_hi(v - bf2f(hi));
    WT[idx] = hi;
    WT[total + idx] = lo;
}

// ---------------- split-bf16 MFMA GEMM: C[M,BN] = A[M,K] @ W[K,BN] ---------
// A fp32 row-major (converted to hi/lo bf16 during LDS staging).
// WT: two bf16 planes (hi, lo) of [BN][Kpad] (BN == full output width here).
// LDS: linear 32-ushort rows, bijective 16B-slot XOR swizzle (conflict-free
// b128 writes AND reads). T14: global loads for step s+1 issue before MFMA(s).

template <int BM, int BN, int WARPS_M, int WARPS_N, int NT>
__global__ __launch_bounds__(NT) void mfma_gemm(const float* __restrict__ A,
                                                const ushort* __restrict__ WT,
                                                float* __restrict__ C,
                                                int M, int K, int Kpad) {
    const int WM = BM / WARPS_M, WN = BN / WARPS_N;
    const int FM = WM / 16, FN = WN / 16;
    const int ACPT = (BM * 4) / NT;      // A 8-ushort chunks per thread
    const int BCPT = (BN * 2 * 4) / NT;  // B chunks per thread (2 planes)
    __shared__ __align__(16) ushort As[2][BM][32];
    __shared__ __align__(16) ushort Bs[2][BN][32];

    int tid = threadIdx.x;
    int lane = tid & 63;
    int w = tid >> 6;
    int wr = w / WARPS_N, wc = w % WARPS_N;
    int bm = blockIdx.y * BM;
    int lrow = lane & 15;
    int lslot = lane >> 4;

    f32x4 acc[FM][FN];
#pragma unroll
    for (int m = 0; m < FM; ++m)
#pragma unroll
        for (int n = 0; n < FN; ++n) acc[m][n] = (f32x4){0.f, 0.f, 0.f, 0.f};

    float4 areg[ACPT][2];
    ulonglong2 breg[BCPT];

    auto load_regs = [&](int s) {
        int k0 = s * 32;
#pragma unroll
        for (int i = 0; i < ACPT; ++i) {
            int ch = tid + i * NT;
            int r = ch >> 2, c = ch & 3;
            int gr = bm + r, gk = k0 + c * 8;
            float4 v0 = make_float4(0.f, 0.f, 0.f, 0.f);
            float4 v1 = v0;
            if (gr < M) {
                const float* p = A + (size_t)gr * K + gk;
                if (gk + 8 <= K) {
                    v0 = *(const float4*)p;
                    v1 = *(const float4*)(p + 4);
                } else {
                    float t[8];
#pragma unroll
                    for (int j = 0; j < 8; ++j) t[j] = (gk + j < K) ? p[j] : 0.0f;
                    v0 = make_float4(t[0], t[1], t[2], t[3]);
                    v1 = make_float4(t[4], t[5], t[6], t[7]);
                }
            }
            areg[i][0] = v0;
            areg[i][1] = v1;
        }
#pragma unroll
        for (int i = 0; i < BCPT; ++i) {
            int ch = tid + i * NT;
            int pl = (ch >= BN * 4) ? 1 : 0;
            int cc = ch - pl * BN * 4;
            int n = cc >> 2, kh = cc & 3;
            breg[i] = *(const ulonglong2*)(WT + (size_t)pl * BN * Kpad +
                                           (size_t)n * Kpad + k0 + kh * 8);
        }
    };

    auto write_regs = [&]() {
#pragma unroll
        for (int i = 0; i < ACPT; ++i) {
            int ch = tid + i * NT;
            int r = ch >> 2, c = ch & 3;
            float fv[8] = {areg[i][0].x, areg[i][0].y, areg[i][0].z, areg[i][0].w,
                           areg[i][1].x, areg[i][1].y, areg[i][1].z, areg[i][1].w};
            union { ushort u[8]; ulonglong2 v; } H, L;
#pragma unroll
            for (int j = 0; j < 8; ++j) {
                ushort h = f2bf_hi(fv[j]);
                H.u[j] = h;
                L.u[j] = f2bf_hi(fv[j] - bf2f(h));
            }
            int sw = SW(r, c) * 8;
            *(ulonglong2*)&As[0][r][sw] = H.v;
            *(ulonglong2*)&As[1][r][sw] = L.v;
        }
#pragma unroll
        for (int i = 0; i < BCPT; ++i) {
            int ch = tid + i * NT;
            int pl = (ch >= BN * 4) ? 1 : 0;
            int cc = ch - pl * BN * 4;
            int n = cc >> 2, kh = cc & 3;
            *(ulonglong2*)&Bs[pl][n][SW(n, kh) * 8] = breg[i];
        }
    };

    auto compute = [&]() {
        bf16x8 af[FM][2], bfr[FN][2];
#pragma unroll
        for (int m = 0; m < FM; ++m) {
            int row = wr * WM + m * 16 + lrow;
            int off = SW(row, lslot) * 8;
            af[m][0] = *(const bf16x8*)&As[0][row][off];
            af[m][1] = *(const bf16x8*)&As[1][row][off];
        }
#pragma unroll
        for (int n = 0; n < FN; ++n) {
            int row = wc * WN + n * 16 + lrow;
            int off = SW(row, lslot) * 8;
            bfr[n][0] = *(const bf16x8*)&Bs[0][row][off];
            bfr[n][1] = *(const bf16x8*)&Bs[1][row][off];
        }
#pragma unroll
        for (int m = 0; m < FM; ++m)
#pragma unroll
            for (int n = 0; n < FN; ++n) {
                acc[m][n] = __builtin_amdgcn_mfma_f32_16x16x32_bf16(af[m][0], bfr[n][0], acc[m][n], 0, 0, 0);
                acc[m][n] = __builtin_amdgcn_mfma_f32_16x16x32_bf16(af[m][0], bfr[n][1], acc[m][n], 0, 0, 0);
                acc[m][n] = __builtin_amdgcn_mfma_f32_16x16x32_bf16(af[m][1], bfr[n][0], acc[m][n], 0, 0, 0);
            }
    };

    const int nsteps = Kpad / 32;
    load_regs(0);
    write_regs();
    __syncthreads();
    for (int s = 0; s < nsteps; ++s) {
        bool more = (s + 1 < nsteps);
        if (more) load_regs(s + 1);   // issue early: latency hides under MFMA
        compute();
        __syncthreads();              // all waves done reading LDS
        if (more) write_regs();       // vmcnt-wait + convert + b128 writes
        __syncthreads();
    }

    // ---- epilogue: C/D layout col=lane&15, row=(lane>>4)*4+i ----
#pragma unroll
    for (int m = 0; m < FM; ++m) {
        int rb = bm + wr * WM + m * 16 + (lane >> 4) * 4;
#pragma unroll
        for (int n = 0; n < FN; ++n) {
            int cb = wc * WN + n * 16 + (lane & 15);
#pragma unroll
            for (int i = 0; i < 4; ++i) {
                int r = rb + i;
                if (r < M) C[(size_t)r * BN + cb] = acc[m][n][i];
            }
        }
    }
}

// ---- gather aggregation: out[d] = selfloop + sum_{p} val[p]*xw[col[p]] ----
template <int F, int LPN, int RELU>
__global__ __launch_bounds__(256) void gather(const int* __restrict__ rowptr,
                                              const int* __restrict__ col,
                                              const float* __restrict__ val,
                                              const float* __restrict__ xw,
                                              const float* __restrict__ dinv,
                                              const float* __restrict__ bias,
                                              float* __restrict__ out, int N) {
    const int NPB = 256 / LPN;
    int d = blockIdx.x * NPB + threadIdx.x / LPN;
    if (d >= N) return;
    int lane = threadIdx.x % LPN;

    float di = dinv[d];
    float w = di * di;
    float4 v = *(const float4*)&xw[(size_t)d * F + lane * 4];
    float a0 = w * v.x, a1 = w * v.y, a2 = w * v.z, a3 = w * v.w;

    int p0 = rowptr[d], p1 = rowptr[d + 1];
    for (int p = p0; p < p1; ++p) {
        int s = col[p];
        float wv = val[p];
        float4 u = *(const float4*)&xw[(size_t)s * F + lane * 4];
        a0 = fmaf(wv, u.x, a0);
        a1 = fmaf(wv, u.y, a1);
        a2 = fmaf(wv, u.z, a2);
        a3 = fmaf(wv, u.w, a3);
    }
    float4 bb = *(const float4*)&bias[lane * 4];
    a0 += bb.x; a1 += bb.y; a2 += bb.z; a3 += bb.w;
    if (RELU) {
        a0 = fmaxf(a0, 0.f); a1 = fmaxf(a1, 0.f);
        a2 = fmaxf(a2, 0.f); a3 = fmaxf(a3, 0.f);
    }
    *(float4*)&out[(size_t)d * F + lane * 4] = make_float4(a0, a1, a2, a3);
}

extern "C" void kernel_launch(void* const* d_in, const int* in_sizes, int n_in,
                              void* d_out, int out_size, void* d_ws, size_t ws_size,
                              hipStream_t stream) {
    const float* x  = (const float*)d_in[0];
    const int*   ei = (const int*)d_in[1];
    const float* ew = (const float*)d_in[2];
    const float* W1 = (const float*)d_in[3];
    const float* b1 = (const float*)d_in[4];
    const float* W2 = (const float*)d_in[5];
    const float* b2 = (const float*)d_in[6];
    float* out = (float*)d_out;

    const int H    = in_sizes[4];            // 256
    const int Fout = in_sizes[6];            // 64
    const int Fin  = in_sizes[3] / H;        // 394
    const int N    = in_sizes[0] / Fin;      // 100000
    const int E    = in_sizes[2];            // 1600000

    const int Kpad1 = (Fin + 31) / 32 * 32;  // 416
    const int Kpad2 = (H + 31) / 32 * 32;    // 256

    const int* src = ei;
    const int* dst = ei + E;

    // workspace layout
    float* ws     = (float*)d_ws;
    float* dinv   = ws;                          // N
    int*   counts = (int*)(dinv + N);            // N
    int*   fillc  = counts + N;                  // N
    int*   rowptr = fillc + N;                   // N+1
    int*   bsums  = rowptr + N + 1;              // 256
    int*   col    = bsums + 256;                 // E
    float* val    = (float*)(col + E);           // E
    float* bufA   = val + E;                     // N*H
    float* bufB   = bufA + (size_t)N * H;        // N*H
    ushort* wt1   = (ushort*)(bufB + (size_t)N * H);  // 2*H*Kpad1
    ushort* wt2   = wt1 + 2 * H * Kpad1;              // 2*Fout*Kpad2

    const int NB = (N + SCAN_TILE - 1) / SCAN_TILE;

    // 1. degrees + histogram + dinv
    init_node<<<(N + 255) / 256, 256, 0, stream>>>(dinv, counts, fillc, N);
    accum_deg_hist<<<(E + 255) / 256, 256, 0, stream>>>(dst, ew, dinv, counts, E);
    compute_dinv<<<(N + 255) / 256, 256, 0, stream>>>(dinv, N);

    // 2. CSR build
    scan1<<<NB, 256, 0, stream>>>(counts, rowptr, bsums, N);
    scan2<<<1, 256, 0, stream>>>(bsums, rowptr, NB, N, E);
    scan3<<<NB, 256, 0, stream>>>(rowptr, bsums, N);
    fill_csr<<<(E + 255) / 256, 256, 0, stream>>>(src, dst, ew, dinv, rowptr, fillc, col, val, E);

    // 3. weight split (hi/lo bf16, transposed)
    split_w<<<(H * Kpad1 + 255) / 256, 256, 0, stream>>>(W1, wt1, Fin, H, Kpad1);
    split_w<<<(Fout * Kpad2 + 255) / 256, 256, 0, stream>>>(W2, wt2, H, Fout, Kpad2);

    // 4. xw1 = x @ W1   [N,394]@[394,256]
    {
        dim3 grid(1, (N + 127) / 128);
        mfma_gemm<128, 256, 2, 4, 512><<<grid, 512, 0, stream>>>(x, wt1, bufA, N, Fin, Kpad1);
    }

    // 5. h = gather + bias + relu
    gather<256, 64, 1><<<(N + 3) / 4, 256, 0, stream>>>(rowptr, col, val, bufA, dinv, b1, bufB, N);

    // 6. xw2 = h @ W2   [N,256]@[256,64]
    {
        dim3 grid(1, (N + 127) / 128);
        mfma_gemm<128, 64, 2, 2, 256><<<grid, 256, 0, stream>>>(bufB, wt2, bufA, N, H, Kpad2);
    }

    // 7. out = gather + bias
    gather<64, 16, 0><<<(N + 15) / 16, 256, 0, stream>>>(rowptr, col, val, bufA, dinv, b2, out, N);
}

// Round 6
// 788.787 us; speedup vs baseline: 9.2041x; 1.1560x over previous
//
#include <hip/hip_runtime.h>
#include <hip/hip_bf16.h>
#include <hip/hip_fp16.h>
#include <type_traits>

// ---------------------------------------------------------------------------
// 2-layer GCN: CSR-gather aggregation (fp16 gathered features, fp32 accum)
// + split-bf16 MFMA GEMMs (fp32 GEMM via hi/lo bf16: Ahi*Bhi+Ahi*Blo+Alo*Bhi)
// ---------------------------------------------------------------------------

typedef __bf16 bf16x8 __attribute__((ext_vector_type(8)));
typedef float f32x4 __attribute__((ext_vector_type(4)));

__device__ inline ushort f2bf_hi(float f) {
    uint u = __float_as_uint(f);
    return (ushort)((u + 0x7fffu + ((u >> 16) & 1u)) >> 16);  // RNE
}
__device__ inline float bf2f(ushort h) { return __uint_as_float(((uint)h) << 16); }

// bijective 16B-slot swizzle within a 16-row x 64B LDS subtile
#define SW(row, slot) ((slot) ^ ((row) & 3) ^ (((row) >> 2) & 3))

// ------------------------- graph preprocessing -----------------------------

__global__ __launch_bounds__(256) void init_node(float* deg, int* counts, int* fillc, int N) {
    int i = blockIdx.x * 256 + threadIdx.x;
    if (i < N) { deg[i] = 1.0f; counts[i] = 0; fillc[i] = 0; }
}

__global__ __launch_bounds__(256) void accum_deg_hist(const int* __restrict__ dst,
                                                      const float* __restrict__ ew,
                                                      float* deg, int* counts, int E) {
    int e = blockIdx.x * 256 + threadIdx.x;
    if (e < E) {
        int d = dst[e];
        atomicAdd(&deg[d], ew[e]);
        atomicAdd(&counts[d], 1);
    }
}

__global__ __launch_bounds__(256) void compute_dinv(float* deg, int N) {
    int i = blockIdx.x * 256 + threadIdx.x;
    if (i < N) deg[i] = rsqrtf(deg[i]);
}

#define SCAN_TILE 2048

__global__ __launch_bounds__(256) void scan1(const int* __restrict__ counts,
                                             int* __restrict__ rowptr,
                                             int* __restrict__ bsums, int N) {
    __shared__ int tmp[256];
    int t = threadIdx.x;
    int base = blockIdx.x * SCAN_TILE + t * 8;
    int v[8], s = 0;
#pragma unroll
    for (int j = 0; j < 8; ++j) { v[j] = (base + j < N) ? counts[base + j] : 0; s += v[j]; }
    tmp[t] = s;
    __syncthreads();
#pragma unroll
    for (int off = 1; off < 256; off <<= 1) {
        int u = (t >= off) ? tmp[t - off] : 0;
        __syncthreads();
        tmp[t] += u;
        __syncthreads();
    }
    int run = tmp[t] - s;
#pragma unroll
    for (int j = 0; j < 8; ++j) {
        if (base + j < N) rowptr[base + j] = run;
        run += v[j];
    }
    if (t == 255) bsums[blockIdx.x] = tmp[255];
}

__global__ __launch_bounds__(256) void scan2(int* bsums, int* rowptr, int NB, int N, int E) {
    __shared__ int tmp[256];
    int t = threadIdx.x;
    int v = (t < NB) ? bsums[t] : 0;
    tmp[t] = v;
    __syncthreads();
#pragma unroll
    for (int off = 1; off < 256; off <<= 1) {
        int u = (t >= off) ? tmp[t - off] : 0;
        __syncthreads();
        tmp[t] += u;
        __syncthreads();
    }
    if (t < NB) bsums[t] = tmp[t] - v;
    if (t == 0) rowptr[N] = E;
}

__global__ __launch_bounds__(256) void scan3(int* rowptr, const int* __restrict__ bsums, int N) {
    int base = blockIdx.x * SCAN_TILE + threadIdx.x * 8;
    int off = bsums[blockIdx.x];
#pragma unroll
    for (int j = 0; j < 8; ++j)
        if (base + j < N) rowptr[base + j] += off;
}

__global__ __launch_bounds__(256) void fill_csr(const int* __restrict__ src,
                                                const int* __restrict__ dst,
                                                const float* __restrict__ ew,
                                                const float* __restrict__ dinv,
                                                const int* __restrict__ rowptr,
                                                int* __restrict__ fillc,
                                                int* __restrict__ col,
                                                float* __restrict__ val, int E) {
    int e = blockIdx.x * 256 + threadIdx.x;
    if (e < E) {
        int d = dst[e], s = src[e];
        int pos = rowptr[d] + atomicAdd(&fillc[d], 1);
        col[pos] = s;
        val[pos] = dinv[s] * ew[e] * dinv[d];
    }
}

// --------- split W[K][N] into bf16 hi/lo planes, transposed [N][Kpad] ------
__global__ __launch_bounds__(256) void split_w(const float* __restrict__ W,
                                               ushort* __restrict__ WT,
                                               int K, int N, int Kpad) {
    int idx = blockIdx.x * 256 + threadIdx.x;
    int total = N * Kpad;
    if (idx >= total) return;
    int n = idx / Kpad, k = idx % Kpad;
    float v = (k < K) ? W[(size_t)k * N + n] : 0.0f;
    ushort hi = f2bf_hi(v);
    ushort lo = f2bf_hi(v - bf2f(hi));
    WT[idx] = hi;
    WT[total + idx] = lo;
}

// ---------------- split-bf16 MFMA GEMM: C[M,BN] = A[M,K] @ W[K,BN] ---------
// A row-major (fp32 or fp16), converted to hi/lo bf16 during LDS staging.
// WT: two bf16 planes (hi, lo) of [BN][Kpad]. OutT: fp32 or fp16 C store.

template <int BM, int BN, int WARPS_M, int WARPS_N, int NT, typename InT, typename OutT>
__global__ __launch_bounds__(NT) void mfma_gemm(const InT* __restrict__ A,
                                                const ushort* __restrict__ WT,
                                                OutT* __restrict__ C,
                                                int M, int K, int Kpad) {
    const int WM = BM / WARPS_M, WN = BN / WARPS_N;
    const int FM = WM / 16, FN = WN / 16;
    const int ACPT = (BM * 4) / NT;      // 8-elem A chunks per thread
    const int BCPT = (BN * 2 * 4) / NT;  // B chunks per thread (2 planes)
    __shared__ __align__(16) ushort As[2][BM][32];
    __shared__ __align__(16) ushort Bs[2][BN][32];

    int tid = threadIdx.x;
    int lane = tid & 63;
    int w = tid >> 6;
    int wr = w / WARPS_N, wc = w % WARPS_N;
    int bm = blockIdx.y * BM;
    int lrow = lane & 15;
    int lslot = lane >> 4;

    f32x4 acc[FM][FN];
#pragma unroll
    for (int m = 0; m < FM; ++m)
#pragma unroll
        for (int n = 0; n < FN; ++n) acc[m][n] = (f32x4){0.f, 0.f, 0.f, 0.f};

    float areg[ACPT][8];
    ulonglong2 breg[BCPT];

    auto load_regs = [&](int s) {
        int k0 = s * 32;
#pragma unroll
        for (int i = 0; i < ACPT; ++i) {
            int ch = tid + i * NT;
            int r = ch >> 2, c = ch & 3;
            int gr = bm + r, gk = k0 + c * 8;
#pragma unroll
            for (int j = 0; j < 8; ++j) areg[i][j] = 0.0f;
            if (gr < M) {
                const InT* p = A + (size_t)gr * K + gk;
                if (gk + 8 <= K) {
                    if constexpr (std::is_same_v<InT, float>) {
                        float4 v0 = *(const float4*)p;
                        float4 v1 = *(const float4*)(p + 4);
                        areg[i][0] = v0.x; areg[i][1] = v0.y; areg[i][2] = v0.z; areg[i][3] = v0.w;
                        areg[i][4] = v1.x; areg[i][5] = v1.y; areg[i][6] = v1.z; areg[i][7] = v1.w;
                    } else {
                        uint4 raw = *(const uint4*)p;  // 8 halfs
                        uint rr[4] = {raw.x, raw.y, raw.z, raw.w};
#pragma unroll
                        for (int j = 0; j < 4; ++j) {
                            __half2 h2 = *(__half2*)&rr[j];
                            float2 f2 = __half22float2(h2);
                            areg[i][j * 2] = f2.x; areg[i][j * 2 + 1] = f2.y;
                        }
                    }
                } else {
#pragma unroll
                    for (int j = 0; j < 8; ++j)
                        if (gk + j < K) areg[i][j] = (float)p[j];
                }
            }
        }
#pragma unroll
        for (int i = 0; i < BCPT; ++i) {
            int ch = tid + i * NT;
            int pl = (ch >= BN * 4) ? 1 : 0;
            int cc = ch - pl * BN * 4;
            int n = cc >> 2, kh = cc & 3;
            breg[i] = *(const ulonglong2*)(WT + (size_t)pl * BN * Kpad +
                                           (size_t)n * Kpad + k0 + kh * 8);
        }
    };

    auto write_regs = [&]() {
#pragma unroll
        for (int i = 0; i < ACPT; ++i) {
            int ch = tid + i * NT;
            int r = ch >> 2, c = ch & 3;
            union { ushort u[8]; ulonglong2 v; } H, L;
#pragma unroll
            for (int j = 0; j < 8; ++j) {
                ushort h = f2bf_hi(areg[i][j]);
                H.u[j] = h;
                L.u[j] = f2bf_hi(areg[i][j] - bf2f(h));
            }
            int sw = SW(r, c) * 8;
            *(ulonglong2*)&As[0][r][sw] = H.v;
            *(ulonglong2*)&As[1][r][sw] = L.v;
        }
#pragma unroll
        for (int i = 0; i < BCPT; ++i) {
            int ch = tid + i * NT;
            int pl = (ch >= BN * 4) ? 1 : 0;
            int cc = ch - pl * BN * 4;
            int n = cc >> 2, kh = cc & 3;
            *(ulonglong2*)&Bs[pl][n][SW(n, kh) * 8] = breg[i];
        }
    };

    auto compute = [&]() {
        bf16x8 af[FM][2], bfr[FN][2];
#pragma unroll
        for (int m = 0; m < FM; ++m) {
            int row = wr * WM + m * 16 + lrow;
            int off = SW(row, lslot) * 8;
            af[m][0] = *(const bf16x8*)&As[0][row][off];
            af[m][1] = *(const bf16x8*)&As[1][row][off];
        }
#pragma unroll
        for (int n = 0; n < FN; ++n) {
            int row = wc * WN + n * 16 + lrow;
            int off = SW(row, lslot) * 8;
            bfr[n][0] = *(const bf16x8*)&Bs[0][row][off];
            bfr[n][1] = *(const bf16x8*)&Bs[1][row][off];
        }
#pragma unroll
        for (int m = 0; m < FM; ++m)
#pragma unroll
            for (int n = 0; n < FN; ++n) {
                acc[m][n] = __builtin_amdgcn_mfma_f32_16x16x32_bf16(af[m][0], bfr[n][0], acc[m][n], 0, 0, 0);
                acc[m][n] = __builtin_amdgcn_mfma_f32_16x16x32_bf16(af[m][0], bfr[n][1], acc[m][n], 0, 0, 0);
                acc[m][n] = __builtin_amdgcn_mfma_f32_16x16x32_bf16(af[m][1], bfr[n][0], acc[m][n], 0, 0, 0);
            }
    };

    const int nsteps = Kpad / 32;
    load_regs(0);
    write_regs();
    __syncthreads();
    for (int s = 0; s < nsteps; ++s) {
        bool more = (s + 1 < nsteps);
        if (more) load_regs(s + 1);   // issue early: latency hides under MFMA
        compute();
        __syncthreads();              // all waves done reading LDS
        if (more) write_regs();       // convert + b128 writes
        __syncthreads();
    }

    // ---- epilogue: C/D layout col=lane&15, row=(lane>>4)*4+i ----
#pragma unroll
    for (int m = 0; m < FM; ++m) {
        int rb = bm + wr * WM + m * 16 + (lane >> 4) * 4;
#pragma unroll
        for (int n = 0; n < FN; ++n) {
            int cb = wc * WN + n * 16 + (lane & 15);
#pragma unroll
            for (int i = 0; i < 4; ++i) {
                int r = rb + i;
                if (r < M) {
                    if constexpr (std::is_same_v<OutT, float>)
                        C[(size_t)r * BN + cb] = acc[m][n][i];
                    else
                        C[(size_t)r * BN + cb] = __float2half(acc[m][n][i]);
                }
            }
        }
    }
}

// ---- gather aggregation (fp16 features, fp32 accum) -----------------------
// out[d] = bias + dinv[d]^2*xw[d] + sum_p val[p]*xw[col[p]]  (; relu)
// LPN lanes per node, each lane owns 4 features (8B half4 loads).
template <int F, int LPN, int RELU, typename OutT>
__global__ __launch_bounds__(256) void gatherh(const int* __restrict__ rowptr,
                                               const int* __restrict__ col,
                                               const float* __restrict__ val,
                                               const __half* __restrict__ xw,
                                               const float* __restrict__ dinv,
                                               const float* __restrict__ bias,
                                               OutT* __restrict__ out, int N) {
    const int NPB = 256 / LPN;
    int d = blockIdx.x * NPB + threadIdx.x / LPN;
    if (d >= N) return;
    int lane = threadIdx.x % LPN;

    float di = dinv[d];
    float w = di * di;

    uint2 raw = *(const uint2*)(xw + (size_t)d * F + lane * 4);
    float2 u0 = __half22float2(*(__half2*)&raw.x);
    float2 u1 = __half22float2(*(__half2*)&raw.y);
    float a0 = w * u0.x, a1 = w * u0.y, a2 = w * u1.x, a3 = w * u1.y;

    int p0 = rowptr[d], p1 = rowptr[d + 1];
    for (int p = p0; p < p1; ++p) {
        int s = col[p];
        float wv = val[p];
        uint2 rv = *(const uint2*)(xw + (size_t)s * F + lane * 4);
        float2 v0 = __half22float2(*(__half2*)&rv.x);
        float2 v1 = __half22float2(*(__half2*)&rv.y);
        a0 = fmaf(wv, v0.x, a0);
        a1 = fmaf(wv, v0.y, a1);
        a2 = fmaf(wv, v1.x, a2);
        a3 = fmaf(wv, v1.y, a3);
    }
    float4 bb = *(const float4*)&bias[lane * 4];
    a0 += bb.x; a1 += bb.y; a2 += bb.z; a3 += bb.w;
    if (RELU) {
        a0 = fmaxf(a0, 0.f); a1 = fmaxf(a1, 0.f);
        a2 = fmaxf(a2, 0.f); a3 = fmaxf(a3, 0.f);
    }
    if constexpr (std::is_same_v<OutT, float>) {
        *(float4*)&out[(size_t)d * F + lane * 4] = make_float4(a0, a1, a2, a3);
    } else {
        __half2 h0 = __floats2half2_rn(a0, a1);
        __half2 h1 = __floats2half2_rn(a2, a3);
        uint2 packed;
        packed.x = *(uint*)&h0;
        packed.y = *(uint*)&h1;
        *(uint2*)&out[(size_t)d * F + lane * 4] = packed;
    }
}

extern "C" void kernel_launch(void* const* d_in, const int* in_sizes, int n_in,
                              void* d_out, int out_size, void* d_ws, size_t ws_size,
                              hipStream_t stream) {
    const float* x  = (const float*)d_in[0];
    const int*   ei = (const int*)d_in[1];
    const float* ew = (const float*)d_in[2];
    const float* W1 = (const float*)d_in[3];
    const float* b1 = (const float*)d_in[4];
    const float* W2 = (const float*)d_in[5];
    const float* b2 = (const float*)d_in[6];
    float* out = (float*)d_out;

    const int H    = in_sizes[4];            // 256
    const int Fout = in_sizes[6];            // 64
    const int Fin  = in_sizes[3] / H;        // 394
    const int N    = in_sizes[0] / Fin;      // 100000
    const int E    = in_sizes[2];            // 1600000

    const int Kpad1 = (Fin + 31) / 32 * 32;  // 416
    const int Kpad2 = (H + 31) / 32 * 32;    // 256

    const int* src = ei;
    const int* dst = ei + E;

    // workspace layout (16B-aligned sections)
    float* ws     = (float*)d_ws;
    float* dinv   = ws;                          // N
    int*   counts = (int*)(dinv + N);            // N
    int*   fillc  = counts + N;                  // N
    int*   rowptr = fillc + N;                   // N+4 (padded)
    int*   bsums  = rowptr + N + 4;              // 256
    int*   col    = bsums + 256;                 // E
    float* val    = (float*)(col + E);           // E
    __half* bufA  = (__half*)(val + E);          // N*H halfs (xw1 / xw2)
    __half* bufB  = bufA + (size_t)N * H;        // N*H halfs (h)
    ushort* wt1   = (ushort*)(bufB + (size_t)N * H);  // 2*H*Kpad1
    ushort* wt2   = wt1 + 2 * H * Kpad1;              // 2*Fout*Kpad2

    const int NB = (N + SCAN_TILE - 1) / SCAN_TILE;

    // 1. degrees + histogram + dinv
    init_node<<<(N + 255) / 256, 256, 0, stream>>>(dinv, counts, fillc, N);
    accum_deg_hist<<<(E + 255) / 256, 256, 0, stream>>>(dst, ew, dinv, counts, E);
    compute_dinv<<<(N + 255) / 256, 256, 0, stream>>>(dinv, N);

    // 2. CSR build
    scan1<<<NB, 256, 0, stream>>>(counts, rowptr, bsums, N);
    scan2<<<1, 256, 0, stream>>>(bsums, rowptr, NB, N, E);
    scan3<<<NB, 256, 0, stream>>>(rowptr, bsums, N);
    fill_csr<<<(E + 255) / 256, 256, 0, stream>>>(src, dst, ew, dinv, rowptr, fillc, col, val, E);

    // 3. weight split (hi/lo bf16, transposed)
    split_w<<<(H * Kpad1 + 255) / 256, 256, 0, stream>>>(W1, wt1, Fin, H, Kpad1);
    split_w<<<(Fout * Kpad2 + 255) / 256, 256, 0, stream>>>(W2, wt2, H, Fout, Kpad2);

    // 4. xw1 = x @ W1   [N,394]@[394,256] -> fp16
    {
        dim3 grid(1, (N + 127) / 128);
        mfma_gemm<128, 256, 2, 4, 512, float, __half>
            <<<grid, 512, 0, stream>>>(x, wt1, bufA, N, Fin, Kpad1);
    }

    // 5. h = gather + bias + relu -> fp16  (one wave per node)
    gatherh<256, 64, 1, __half><<<(N + 3) / 4, 256, 0, stream>>>(
        rowptr, col, val, bufA, dinv, b1, bufB, N);

    // 6. xw2 = h @ W2   [N,256]@[256,64] -> fp16
    {
        dim3 grid(1, (N + 127) / 128);
        mfma_gemm<128, 64, 2, 2, 256, __half, __half>
            <<<grid, 256, 0, stream>>>(bufB, wt2, bufA, N, H, Kpad2);
    }

    // 7. out = gather + bias -> fp32
    gatherh<64, 16, 0, float><<<(N + 15) / 16, 256, 0, stream>>>(
        rowptr, col, val, bufA, dinv, b2, out, N);
}

// Round 7
// 768.222 us; speedup vs baseline: 9.4505x; 1.0268x over previous
//
#include <hip/hip_runtime.h>
#include <hip/hip_bf16.h>
#include <hip/hip_fp16.h>
#include <type_traits>

// ---------------------------------------------------------------------------
// 2-layer GCN. CSR-gather aggregation (fp16 gathered features, fp32 accum).
// GEMMs: pure-bf16 3-product MFMA (hi/lo split precomputed in global planes):
//   C = Ahi*Bhi + Ahi*Blo + Alo*Bhi   (~17-bit effective mantissa)
// Staging: global_load_lds (16B DMA), linear LDS dest, source-swizzled so
// swizzled ds_read_b128 fragment reads are bank-conflict-free (rule 21).
// ---------------------------------------------------------------------------

typedef __bf16 bf16x8 __attribute__((ext_vector_type(8)));
typedef float f32x4 __attribute__((ext_vector_type(4)));

__device__ inline ushort f2bf_hi(float f) {
    uint u = __float_as_uint(f);
    return (ushort)((u + 0x7fffu + ((u >> 16) & 1u)) >> 16);  // RNE
}
__device__ inline float bf2f(ushort h) { return __uint_as_float(((uint)h) << 16); }

__device__ inline void async_copy16(const void* g, void* l) {
    __builtin_amdgcn_global_load_lds(
        (const __attribute__((address_space(1))) void*)g,
        (__attribute__((address_space(3))) void*)l, 16, 0, 0);
}

// ------------------------- graph preprocessing -----------------------------

__global__ __launch_bounds__(256) void init_node(float* deg, int* counts, int* fillc, int N) {
    int i = blockIdx.x * 256 + threadIdx.x;
    if (i < N) { deg[i] = 1.0f; counts[i] = 0; fillc[i] = 0; }
}

__global__ __launch_bounds__(256) void accum_deg_hist(const int* __restrict__ dst,
                                                      const float* __restrict__ ew,
                                                      float* deg, int* counts, int E) {
    int e = blockIdx.x * 256 + threadIdx.x;
    if (e < E) {
        int d = dst[e];
        atomicAdd(&deg[d], ew[e]);
        atomicAdd(&counts[d], 1);
    }
}

__global__ __launch_bounds__(256) void compute_dinv(float* deg, int N) {
    int i = blockIdx.x * 256 + threadIdx.x;
    if (i < N) deg[i] = rsqrtf(deg[i]);
}

#define SCAN_TILE 2048

__global__ __launch_bounds__(256) void scan1(const int* __restrict__ counts,
                                             int* __restrict__ rowptr,
                                             int* __restrict__ bsums, int N) {
    __shared__ int tmp[256];
    int t = threadIdx.x;
    int base = blockIdx.x * SCAN_TILE + t * 8;
    int v[8], s = 0;
#pragma unroll
    for (int j = 0; j < 8; ++j) { v[j] = (base + j < N) ? counts[base + j] : 0; s += v[j]; }
    tmp[t] = s;
    __syncthreads();
#pragma unroll
    for (int off = 1; off < 256; off <<= 1) {
        int u = (t >= off) ? tmp[t - off] : 0;
        __syncthreads();
        tmp[t] += u;
        __syncthreads();
    }
    int run = tmp[t] - s;
#pragma unroll
    for (int j = 0; j < 8; ++j) {
        if (base + j < N) rowptr[base + j] = run;
        run += v[j];
    }
    if (t == 255) bsums[blockIdx.x] = tmp[255];
}

__global__ __launch_bounds__(256) void scan2(int* bsums, int* rowptr, int NB, int N, int E) {
    __shared__ int tmp[256];
    int t = threadIdx.x;
    int v = (t < NB) ? bsums[t] : 0;
    tmp[t] = v;
    __syncthreads();
#pragma unroll
    for (int off = 1; off < 256; off <<= 1) {
        int u = (t >= off) ? tmp[t - off] : 0;
        __syncthreads();
        tmp[t] += u;
        __syncthreads();
    }
    if (t < NB) bsums[t] = tmp[t] - v;
    if (t == 0) rowptr[N] = E;
}

__global__ __launch_bounds__(256) void scan3(int* rowptr, const int* __restrict__ bsums, int N) {
    int base = blockIdx.x * SCAN_TILE + threadIdx.x * 8;
    int off = bsums[blockIdx.x];
#pragma unroll
    for (int j = 0; j < 8; ++j)
        if (base + j < N) rowptr[base + j] += off;
}

__global__ __launch_bounds__(256) void fill_csr(const int* __restrict__ src,
                                                const int* __restrict__ dst,
                                                const float* __restrict__ ew,
                                                const float* __restrict__ dinv,
                                                const int* __restrict__ rowptr,
                                                int* __restrict__ fillc,
                                                int* __restrict__ col,
                                                float* __restrict__ val, int E) {
    int e = blockIdx.x * 256 + threadIdx.x;
    if (e < E) {
        int d = dst[e], s = src[e];
        int pos = rowptr[d] + atomicAdd(&fillc[d], 1);
        col[pos] = s;
        val[pos] = dinv[s] * ew[e] * dinv[d];
    }
}

// --------- split W[K][N] into bf16 hi/lo planes, transposed [N][Kpad] ------
__global__ __launch_bounds__(256) void split_w(const float* __restrict__ W,
                                               ushort* __restrict__ WT,
                                               int K, int N, int Kpad) {
    int idx = blockIdx.x * 256 + threadIdx.x;
    int total = N * Kpad;
    if (idx >= total) return;
    int n = idx / Kpad, k = idx % Kpad;
    float v = (k < K) ? W[(size_t)k * N + n] : 0.0f;
    ushort hi = f2bf_hi(v);
    ushort lo = f2bf_hi(v - bf2f(hi));
    WT[idx] = hi;
    WT[total + idx] = lo;
}

// --------- split x[N][K] fp32 -> Xhi/Xlo bf16 planes [N][Kpad] -------------
__global__ __launch_bounds__(256) void split_x(const float* __restrict__ x,
                                               ushort* __restrict__ Xhi,
                                               ushort* __restrict__ Xlo,
                                               int Nn, int K, int Kpad) {
    int idx = blockIdx.x * 256 + threadIdx.x;  // one 8-elem chunk
    int cpr = Kpad / 8;
    int total = Nn * cpr;
    if (idx >= total) return;
    int row = idx / cpr, c = idx % cpr;
    int gk = c * 8;
    const float* p = x + (size_t)row * K + gk;
    float v[8];
    if (gk + 8 <= K) {
#pragma unroll
        for (int j = 0; j < 4; ++j) {
            float2 t2 = *(const float2*)(p + j * 2);  // 8B aligned always
            v[j * 2] = t2.x; v[j * 2 + 1] = t2.y;
        }
    } else {
#pragma unroll
        for (int j = 0; j < 8; ++j) v[j] = (gk + j < K) ? p[j] : 0.0f;
    }
    union { ushort u[4]; uint2 v2; } H0, H1, L0, L1;
#pragma unroll
    for (int j = 0; j < 4; ++j) {
        ushort h = f2bf_hi(v[j]);
        H0.u[j] = h; L0.u[j] = f2bf_hi(v[j] - bf2f(h));
        ushort h2 = f2bf_hi(v[4 + j]);
        H1.u[j] = h2; L1.u[j] = f2bf_hi(v[4 + j] - bf2f(h2));
    }
    size_t o = (size_t)row * Kpad + gk;
    *(uint2*)&Xhi[o] = H0.v2; *(uint2*)&Xhi[o + 4] = H1.v2;
    *(uint2*)&Xlo[o] = L0.v2; *(uint2*)&Xlo[o + 4] = L1.v2;
}

// ---------------- pure-bf16 3-product MFMA GEMM ----------------------------
// C[M,BN](fp16) = A @ W where A given as Ahi/Alo planes [M][Kpad],
// W as WT = [2][BN][Kpad] planes. Staging via global_load_lds, LDS linear,
// source pre-swizzled with p = slot ^ ((row>>1)&3) (involution; read uses same).

template <int BM, int BN, int WARPS_M, int WARPS_N, int NT>
__global__ __launch_bounds__(NT) void mfma_gemm3(const ushort* __restrict__ Ahi,
                                                 const ushort* __restrict__ Alo,
                                                 const ushort* __restrict__ WT,
                                                 __half* __restrict__ C,
                                                 int M, int Kpad) {
    const int WM = BM / WARPS_M, WN = BN / WARPS_N;
    const int FM = WM / 16, FN = WN / 16;
    const int ACH = BM * 4;                 // 16B chunks per A plane
    const int BCH = BN * 4;                 // per B plane
    const int TOTCH = 2 * ACH + 2 * BCH;
    const int CH = TOTCH / NT;              // chunks per thread
    __shared__ __align__(16) ushort lds[TOTCH * 8];

    int tid = threadIdx.x;
    int lane = tid & 63;
    int w = tid >> 6;
    int wr = w / WARPS_N, wc = w % WARPS_N;
    int bm = blockIdx.y * BM;
    int lrow = lane & 15;
    int lslot = lane >> 4;

    // per-thread staging source pointers (at k0=0); LDS dest is linear chunk id
    const ushort* srcp[CH];
#pragma unroll
    for (int i = 0; i < CH; ++i) {
        int ch = tid + i * NT;
        int c = ch;
        const ushort* base;
        int row;
        if (c < ACH)               { base = Ahi; row = c >> 2; }
        else if (c < 2 * ACH)      { c -= ACH; base = Alo; row = c >> 2; }
        else if (c < 2 * ACH + BCH){ c -= 2 * ACH; base = WT; row = c >> 2; }
        else                       { c -= 2 * ACH + BCH; base = WT + (size_t)BN * Kpad; row = c >> 2; }
        int p = c & 3;
        int s = p ^ ((row >> 1) & 3);       // inverse swizzle on source
        int grow;
        if (ch < 2 * ACH) { grow = bm + row; if (grow > M - 1) grow = M - 1; }
        else grow = row;
        srcp[i] = base + (size_t)grow * Kpad + s * 8;
    }

    f32x4 acc[FM][FN];
#pragma unroll
    for (int m = 0; m < FM; ++m)
#pragma unroll
        for (int n = 0; n < FN; ++n) acc[m][n] = (f32x4){0.f, 0.f, 0.f, 0.f};

    auto stage = [&]() {
#pragma unroll
        for (int i = 0; i < CH; ++i) {
            ushort* dstbase = (ushort*)lds + (size_t)((tid & ~63) + i * NT) * 8;
            async_copy16(srcp[i], dstbase);
            srcp[i] += 32;                  // next K-slice
        }
    };

    auto compute = [&]() {
        bf16x8 ah[FM], al[FM], bh[FN], bl[FN];
#pragma unroll
        for (int m = 0; m < FM; ++m) {
            int row = wr * WM + m * 16 + lrow;
            int p = lslot ^ ((row >> 1) & 3);
            ah[m] = *(const bf16x8*)&lds[(size_t)(row * 4 + p) * 8];
            al[m] = *(const bf16x8*)&lds[(size_t)(ACH + row * 4 + p) * 8];
        }
#pragma unroll
        for (int n = 0; n < FN; ++n) {
            int row = wc * WN + n * 16 + lrow;
            int p = lslot ^ ((row >> 1) & 3);
            bh[n] = *(const bf16x8*)&lds[(size_t)(2 * ACH + row * 4 + p) * 8];
            bl[n] = *(const bf16x8*)&lds[(size_t)(2 * ACH + BCH + row * 4 + p) * 8];
        }
#pragma unroll
        for (int m = 0; m < FM; ++m)
#pragma unroll
            for (int n = 0; n < FN; ++n) {
                acc[m][n] = __builtin_amdgcn_mfma_f32_16x16x32_bf16(ah[m], bh[n], acc[m][n], 0, 0, 0);
                acc[m][n] = __builtin_amdgcn_mfma_f32_16x16x32_bf16(ah[m], bl[n], acc[m][n], 0, 0, 0);
                acc[m][n] = __builtin_amdgcn_mfma_f32_16x16x32_bf16(al[m], bh[n], acc[m][n], 0, 0, 0);
            }
    };

    const int nsteps = Kpad / 32;
    stage();
    for (int s = 0; s < nsteps; ++s) {
        asm volatile("s_waitcnt vmcnt(0)" ::: "memory");
        __syncthreads();                    // staged data visible to all
        compute();
        if (s + 1 < nsteps) {
            __syncthreads();                // all waves done reading LDS
            stage();                        // async DMA next slice
        }
    }

    // ---- epilogue: C/D layout col=lane&15, row=(lane>>4)*4+i ----
#pragma unroll
    for (int m = 0; m < FM; ++m) {
        int rb = bm + wr * WM + m * 16 + (lane >> 4) * 4;
#pragma unroll
        for (int n = 0; n < FN; ++n) {
            int cb = wc * WN + n * 16 + (lane & 15);
#pragma unroll
            for (int i = 0; i < 4; ++i) {
                int r = rb + i;
                if (r < M) C[(size_t)r * BN + cb] = __float2half(acc[m][n][i]);
            }
        }
    }
}

// ---- layer-1 gather: fp16 features in, bf16 hi/lo planes out --------------
// h[d] = relu(bias + dinv[d]^2*xw[d] + sum_p val[p]*xw[col[p]])
__global__ __launch_bounds__(256) void gather_split(const int* __restrict__ rowptr,
                                                    const int* __restrict__ col,
                                                    const float* __restrict__ val,
                                                    const __half* __restrict__ xw,
                                                    const float* __restrict__ dinv,
                                                    const float* __restrict__ bias,
                                                    ushort* __restrict__ Hhi,
                                                    ushort* __restrict__ Hlo,
                                                    int N) {
    int d = blockIdx.x * 4 + (threadIdx.x >> 6);  // one wave per node, F=256
    if (d >= N) return;
    int lane = threadIdx.x & 63;

    float di = dinv[d];
    float w = di * di;
    uint2 raw = *(const uint2*)(xw + (size_t)d * 256 + lane * 4);
    float2 u0 = __half22float2(*(__half2*)&raw.x);
    float2 u1 = __half22float2(*(__half2*)&raw.y);
    float a0 = w * u0.x, a1 = w * u0.y, a2 = w * u1.x, a3 = w * u1.y;

    int p0 = rowptr[d], p1 = rowptr[d + 1];
    for (int p = p0; p < p1; ++p) {
        int s = col[p];
        float wv = val[p];
        uint2 rv = *(const uint2*)(xw + (size_t)s * 256 + lane * 4);
        float2 v0 = __half22float2(*(__half2*)&rv.x);
        float2 v1 = __half22float2(*(__half2*)&rv.y);
        a0 = fmaf(wv, v0.x, a0);
        a1 = fmaf(wv, v0.y, a1);
        a2 = fmaf(wv, v1.x, a2);
        a3 = fmaf(wv, v1.y, a3);
    }
    float4 bb = *(const float4*)&bias[lane * 4];
    a0 = fmaxf(a0 + bb.x, 0.f);
    a1 = fmaxf(a1 + bb.y, 0.f);
    a2 = fmaxf(a2 + bb.z, 0.f);
    a3 = fmaxf(a3 + bb.w, 0.f);

    union { ushort u[4]; uint2 v2; } H, L;
    float av[4] = {a0, a1, a2, a3};
#pragma unroll
    for (int j = 0; j < 4; ++j) {
        ushort h = f2bf_hi(av[j]);
        H.u[j] = h;
        L.u[j] = f2bf_hi(av[j] - bf2f(h));
    }
    size_t o = (size_t)d * 256 + lane * 4;
    *(uint2*)&Hhi[o] = H.v2;
    *(uint2*)&Hlo[o] = L.v2;
}

// ---- layer-2 gather: fp16 features in, fp32 out ---------------------------
template <int F, int LPN>
__global__ __launch_bounds__(256) void gatherh(const int* __restrict__ rowptr,
                                               const int* __restrict__ col,
                                               const float* __restrict__ val,
                                               const __half* __restrict__ xw,
                                               const float* __restrict__ dinv,
                                               const float* __restrict__ bias,
                                               float* __restrict__ out, int N) {
    const int NPB = 256 / LPN;
    int d = blockIdx.x * NPB + threadIdx.x / LPN;
    if (d >= N) return;
    int lane = threadIdx.x % LPN;

    float di = dinv[d];
    float w = di * di;
    uint2 raw = *(const uint2*)(xw + (size_t)d * F + lane * 4);
    float2 u0 = __half22float2(*(__half2*)&raw.x);
    float2 u1 = __half22float2(*(__half2*)&raw.y);
    float a0 = w * u0.x, a1 = w * u0.y, a2 = w * u1.x, a3 = w * u1.y;

    int p0 = rowptr[d], p1 = rowptr[d + 1];
    for (int p = p0; p < p1; ++p) {
        int s = col[p];
        float wv = val[p];
        uint2 rv = *(const uint2*)(xw + (size_t)s * F + lane * 4);
        float2 v0 = __half22float2(*(__half2*)&rv.x);
        float2 v1 = __half22float2(*(__half2*)&rv.y);
        a0 = fmaf(wv, v0.x, a0);
        a1 = fmaf(wv, v0.y, a1);
        a2 = fmaf(wv, v1.x, a2);
        a3 = fmaf(wv, v1.y, a3);
    }
    float4 bb = *(const float4*)&bias[lane * 4];
    a0 += bb.x; a1 += bb.y; a2 += bb.z; a3 += bb.w;
    *(float4*)&out[(size_t)d * F + lane * 4] = make_float4(a0, a1, a2, a3);
}

extern "C" void kernel_launch(void* const* d_in, const int* in_sizes, int n_in,
                              void* d_out, int out_size, void* d_ws, size_t ws_size,
                              hipStream_t stream) {
    const float* x  = (const float*)d_in[0];
    const int*   ei = (const int*)d_in[1];
    const float* ew = (const float*)d_in[2];
    const float* W1 = (const float*)d_in[3];
    const float* b1 = (const float*)d_in[4];
    const float* W2 = (const float*)d_in[5];
    const float* b2 = (const float*)d_in[6];
    float* out = (float*)d_out;

    const int H    = in_sizes[4];            // 256
    const int Fout = in_sizes[6];            // 64
    const int Fin  = in_sizes[3] / H;        // 394
    const int N    = in_sizes[0] / Fin;      // 100000
    const int E    = in_sizes[2];            // 1600000

    const int Kpad1 = (Fin + 31) / 32 * 32;  // 416
    const int Kpad2 = (H + 31) / 32 * 32;    // 256

    const int* src = ei;
    const int* dst = ei + E;

    // workspace layout (all sections 16B aligned)
    float* ws     = (float*)d_ws;
    float* dinv   = ws;                           // N
    int*   counts = (int*)(dinv + N);             // N
    int*   fillc  = counts + N;                   // N
    int*   rowptr = fillc + N;                    // N+4
    int*   bsums  = rowptr + N + 4;               // 256
    int*   col    = bsums + 256;                  // E
    float* val    = (float*)(col + E);            // E
    __half* bufA  = (__half*)(val + E);           // N*H halfs (xw1, later xw2)
    ushort* plane = (ushort*)(bufA + (size_t)N * H);
    // plane region reused: Xhi/Xlo (N*Kpad1 each) then Hhi/Hlo (N*Kpad2 each)
    ushort* Xhi = plane;
    ushort* Xlo = plane + (size_t)N * Kpad1;
    ushort* Hhi = plane;
    ushort* Hlo = plane + (size_t)N * Kpad2;
    ushort* wt1 = plane + 2 * (size_t)N * Kpad1;  // 2*H*Kpad1
    ushort* wt2 = wt1 + 2 * H * Kpad1;            // 2*Fout*Kpad2

    const int NB = (N + SCAN_TILE - 1) / SCAN_TILE;

    // 1. degrees + histogram + dinv
    init_node<<<(N + 255) / 256, 256, 0, stream>>>(dinv, counts, fillc, N);
    accum_deg_hist<<<(E + 255) / 256, 256, 0, stream>>>(dst, ew, dinv, counts, E);
    compute_dinv<<<(N + 255) / 256, 256, 0, stream>>>(dinv, N);

    // 2. CSR build
    scan1<<<NB, 256, 0, stream>>>(counts, rowptr, bsums, N);
    scan2<<<1, 256, 0, stream>>>(bsums, rowptr, NB, N, E);
    scan3<<<NB, 256, 0, stream>>>(rowptr, bsums, N);
    fill_csr<<<(E + 255) / 256, 256, 0, stream>>>(src, dst, ew, dinv, rowptr, fillc, col, val, E);

    // 3. weight split + x split (hi/lo bf16 planes)
    split_w<<<(H * Kpad1 + 255) / 256, 256, 0, stream>>>(W1, wt1, Fin, H, Kpad1);
    split_w<<<(Fout * Kpad2 + 255) / 256, 256, 0, stream>>>(W2, wt2, H, Fout, Kpad2);
    split_x<<<((size_t)N * (Kpad1 / 8) + 255) / 256, 256, 0, stream>>>(x, Xhi, Xlo, N, Fin, Kpad1);

    // 4. xw1 = x @ W1   [N,394]@[394,256] -> fp16
    {
        dim3 grid(1, (N + 127) / 128);
        mfma_gemm3<128, 256, 2, 4, 512><<<grid, 512, 0, stream>>>(Xhi, Xlo, wt1, bufA, N, Kpad1);
    }

    // 5. h = relu(gather + bias) -> bf16 hi/lo planes (overwrites X planes)
    gather_split<<<(N + 3) / 4, 256, 0, stream>>>(rowptr, col, val, bufA, dinv, b1, Hhi, Hlo, N);

    // 6. xw2 = h @ W2   [N,256]@[256,64] -> fp16
    {
        dim3 grid(1, (N + 127) / 128);
        mfma_gemm3<128, 64, 2, 2, 256><<<grid, 256, 0, stream>>>(Hhi, Hlo, wt2, bufA, N, Kpad2);
    }

    // 7. out = gather + bias -> fp32
    gatherh<64, 16><<<(N + 15) / 16, 256, 0, stream>>>(rowptr, col, val, bufA, dinv, b2, out, N);
}

// Round 8
// 632.173 us; speedup vs baseline: 11.4843x; 1.2152x over previous
//
#include <hip/hip_runtime.h>
#include <hip/hip_bf16.h>
#include <hip/hip_fp16.h>
#include <type_traits>

// ---------------------------------------------------------------------------
// 2-layer GCN. CSR-gather aggregation (fp16 gathered features, fp32 accum).
// GEMMs: single-product fp16 MFMA (fp32 accumulate) — tolerance is bf16-scaled
// and intermediates are already fp16, so split-bf16 tricks are wasted work.
// GEMM staging: global_load_lds 16B DMA, double-buffered LDS, counted
// vmcnt(3) + raw s_barrier (loads for step s+1 stay in flight across compute).
// ---------------------------------------------------------------------------

typedef _Float16 f16x8 __attribute__((ext_vector_type(8)));
typedef float f32x4 __attribute__((ext_vector_type(4)));

__device__ inline void async_copy16(const void* g, void* l) {
    __builtin_amdgcn_global_load_lds(
        (const __attribute__((address_space(1))) void*)g,
        (__attribute__((address_space(3))) void*)l, 16, 0, 0);
}

// ------------------------- graph preprocessing -----------------------------

__global__ __launch_bounds__(256) void init_node(float* deg, int* counts, int* fillc, int N) {
    int i = blockIdx.x * 256 + threadIdx.x;
    if (i < N) { deg[i] = 1.0f; counts[i] = 0; fillc[i] = 0; }
}

__global__ __launch_bounds__(256) void accum_deg_hist(const int* __restrict__ dst,
                                                      const float* __restrict__ ew,
                                                      float* deg, int* counts, int E) {
    int e = blockIdx.x * 256 + threadIdx.x;
    if (e < E) {
        int d = dst[e];
        atomicAdd(&deg[d], ew[e]);
        atomicAdd(&counts[d], 1);
    }
}

__global__ __launch_bounds__(256) void compute_dinv(float* deg, int N) {
    int i = blockIdx.x * 256 + threadIdx.x;
    if (i < N) deg[i] = rsqrtf(deg[i]);
}

#define SCAN_TILE 2048

__global__ __launch_bounds__(256) void scan1(const int* __restrict__ counts,
                                             int* __restrict__ rowptr,
                                             int* __restrict__ bsums, int N) {
    __shared__ int tmp[256];
    int t = threadIdx.x;
    int base = blockIdx.x * SCAN_TILE + t * 8;
    int v[8], s = 0;
#pragma unroll
    for (int j = 0; j < 8; ++j) { v[j] = (base + j < N) ? counts[base + j] : 0; s += v[j]; }
    tmp[t] = s;
    __syncthreads();
#pragma unroll
    for (int off = 1; off < 256; off <<= 1) {
        int u = (t >= off) ? tmp[t - off] : 0;
        __syncthreads();
        tmp[t] += u;
        __syncthreads();
    }
    int run = tmp[t] - s;
#pragma unroll
    for (int j = 0; j < 8; ++j) {
        if (base + j < N) rowptr[base + j] = run;
        run += v[j];
    }
    if (t == 255) bsums[blockIdx.x] = tmp[255];
}

__global__ __launch_bounds__(256) void scan2(int* bsums, int* rowptr, int NB, int N, int E) {
    __shared__ int tmp[256];
    int t = threadIdx.x;
    int v = (t < NB) ? bsums[t] : 0;
    tmp[t] = v;
    __syncthreads();
#pragma unroll
    for (int off = 1; off < 256; off <<= 1) {
        int u = (t >= off) ? tmp[t - off] : 0;
        __syncthreads();
        tmp[t] += u;
        __syncthreads();
    }
    if (t < NB) bsums[t] = tmp[t] - v;
    if (t == 0) rowptr[N] = E;
}

__global__ __launch_bounds__(256) void scan3(int* rowptr, const int* __restrict__ bsums, int N) {
    int base = blockIdx.x * SCAN_TILE + threadIdx.x * 8;
    int off = bsums[blockIdx.x];
#pragma unroll
    for (int j = 0; j < 8; ++j)
        if (base + j < N) rowptr[base + j] += off;
}

__global__ __launch_bounds__(256) void fill_csr(const int* __restrict__ src,
                                                const int* __restrict__ dst,
                                                const float* __restrict__ ew,
                                                const float* __restrict__ dinv,
                                                const int* __restrict__ rowptr,
                                                int* __restrict__ fillc,
                                                int* __restrict__ col,
                                                float* __restrict__ val, int E) {
    int e = blockIdx.x * 256 + threadIdx.x;
    if (e < E) {
        int d = dst[e], s = src[e];
        int pos = rowptr[d] + atomicAdd(&fillc[d], 1);
        col[pos] = s;
        val[pos] = dinv[s] * ew[e] * dinv[d];
    }
}

// --------- W[K][N] fp32 -> fp16 transposed [N][Kpad] (zero-padded K) -------
__global__ __launch_bounds__(256) void tohalf_w(const float* __restrict__ W,
                                                __half* __restrict__ WT,
                                                int K, int N, int Kpad) {
    int idx = blockIdx.x * 256 + threadIdx.x;
    int total = N * Kpad;
    if (idx >= total) return;
    int n = idx / Kpad, k = idx % Kpad;
    float v = (k < K) ? W[(size_t)k * N + n] : 0.0f;
    WT[idx] = __float2half(v);
}

// --------- x[N][K] fp32 -> fp16 [N][Kpad] ----------------------------------
__global__ __launch_bounds__(256) void tohalf_x(const float* __restrict__ x,
                                                __half* __restrict__ Xh,
                                                int Nn, int K, int Kpad) {
    int idx = blockIdx.x * 256 + threadIdx.x;  // one 8-elem chunk
    int cpr = Kpad / 8;
    int total = Nn * cpr;
    if (idx >= total) return;
    int row = idx / cpr, c = idx % cpr;
    int gk = c * 8;
    const float* p = x + (size_t)row * K + gk;
    float v[8];
    if (gk + 8 <= K) {
#pragma unroll
        for (int j = 0; j < 4; ++j) {
            float2 t2 = *(const float2*)(p + j * 2);  // 8B-aligned always
            v[j * 2] = t2.x; v[j * 2 + 1] = t2.y;
        }
    } else {
#pragma unroll
        for (int j = 0; j < 8; ++j) v[j] = (gk + j < K) ? p[j] : 0.0f;
    }
    union { __half2 h[4]; uint4 u; } pk;
#pragma unroll
    for (int j = 0; j < 4; ++j) pk.h[j] = __floats2half2_rn(v[j * 2], v[j * 2 + 1]);
    *(uint4*)&Xh[(size_t)row * Kpad + gk] = pk.u;
}

// ---------------- fp16 MFMA GEMM: C[M,BN](fp16) = A[M,Kpad] @ BT^T ---------
// A, BT fp16; BT is [BN][Kpad] (transposed W). Double-buffered LDS via
// global_load_lds; source pre-swizzled with involution p = slot^((row>>1)&3)
// so swizzled ds_read_b128 fragment reads are 2-way max (free).

template <int BM, int BN, int WARPS_M, int WARPS_N, int NT>
__global__ __launch_bounds__(NT) void gemm_f16(const __half* __restrict__ Ah,
                                               const __half* __restrict__ BT,
                                               __half* __restrict__ C,
                                               int M, int Kpad) {
    const int WM = BM / WARPS_M, WN = BN / WARPS_N;
    const int FM = WM / 16, FN = WN / 16;
    const int ACH = BM * 4;              // 16B chunks for A tile
    const int BCH = BN * 4;              // for B tile
    const int TOTCH = ACH + BCH;
    const int CH = TOTCH / NT;
    static_assert(CH == 3, "vmcnt(3) hardcoded below");
    __shared__ __align__(16) __half lds[2][TOTCH * 8];

    int tid = threadIdx.x;
    int lane = tid & 63;
    int w = tid >> 6;
    int wr = w / WARPS_N, wc = w % WARPS_N;
    int bm = blockIdx.x * BM;
    int lrow = lane & 15;
    int lslot = lane >> 4;

    // per-thread staging source pointers (k0 = 0); LDS dest is linear chunk id
    const __half* srcp[CH];
#pragma unroll
    for (int i = 0; i < CH; ++i) {
        int ch = tid + i * NT;
        if (ch < ACH) {
            int c = ch, row = c >> 2;
            int grow = bm + row;
            if (grow >= M) grow = M - 1;
            srcp[i] = Ah + (size_t)grow * Kpad + (size_t)(((c & 3) ^ ((row >> 1) & 3)) * 8);
        } else {
            int c = ch - ACH, row = c >> 2;
            srcp[i] = BT + (size_t)row * Kpad + (size_t)(((c & 3) ^ ((row >> 1) & 3)) * 8);
        }
    }

    f32x4 acc[FM][FN];
#pragma unroll
    for (int m = 0; m < FM; ++m)
#pragma unroll
        for (int n = 0; n < FN; ++n) acc[m][n] = (f32x4){0.f, 0.f, 0.f, 0.f};

    auto stage = [&](int buf) {
#pragma unroll
        for (int i = 0; i < CH; ++i) {
            async_copy16(srcp[i], &lds[buf][(size_t)((tid & ~63) + i * NT) * 8]);
            srcp[i] += 32;               // next 32-wide K slice
        }
    };

    auto compute = [&](int buf) {
        f16x8 af[FM], bf[FN];
#pragma unroll
        for (int m = 0; m < FM; ++m) {
            int row = wr * WM + m * 16 + lrow;
            int p = lslot ^ ((row >> 1) & 3);
            af[m] = *(const f16x8*)&lds[buf][(size_t)(row * 4 + p) * 8];
        }
#pragma unroll
        for (int n = 0; n < FN; ++n) {
            int row = wc * WN + n * 16 + lrow;
            int p = lslot ^ ((row >> 1) & 3);
            bf[n] = *(const f16x8*)&lds[buf][(size_t)(ACH + row * 4 + p) * 8];
        }
#pragma unroll
        for (int m = 0; m < FM; ++m)
#pragma unroll
            for (int n = 0; n < FN; ++n)
                acc[m][n] = __builtin_amdgcn_mfma_f32_16x16x32_f16(af[m], bf[n], acc[m][n], 0, 0, 0);
    };

    const int nsteps = Kpad / 32;
    stage(0);
    for (int s = 0; s < nsteps; ++s) {
        if (s + 1 < nsteps) {
            stage((s + 1) & 1);          // issue next-step DMAs first
            asm volatile("s_waitcnt vmcnt(3)" ::: "memory");  // cur landed, 3 in flight
        } else {
            asm volatile("s_waitcnt vmcnt(0)" ::: "memory");
        }
        __builtin_amdgcn_s_barrier();    // raw: no compiler vmcnt(0) drain
        compute(s & 1);
        // compiler's lgkm waits before MFMA operand use ensure ds_reads retired
        __builtin_amdgcn_s_barrier();    // safe to overwrite this buf next iter
    }

    // ---- epilogue: C/D layout col=lane&15, row=(lane>>4)*4+i ----
#pragma unroll
    for (int m = 0; m < FM; ++m) {
        int rb = bm + wr * WM + m * 16 + (lane >> 4) * 4;
#pragma unroll
        for (int n = 0; n < FN; ++n) {
            int cb = wc * WN + n * 16 + (lane & 15);
#pragma unroll
            for (int i = 0; i < 4; ++i) {
                int r = rb + i;
                if (r < M) C[(size_t)r * BN + cb] = __float2half(acc[m][n][i]);
            }
        }
    }
}

// ---- gather aggregation (fp16 features, fp32 accum) -----------------------
// out[d] = bias + dinv[d]^2*xw[d] + sum_p val[p]*xw[col[p]]  (; relu)
template <int F, int LPN, int RELU, typename OutT>
__global__ __launch_bounds__(256) void gatherh(const int* __restrict__ rowptr,
                                               const int* __restrict__ col,
                                               const float* __restrict__ val,
                                               const __half* __restrict__ xw,
                                               const float* __restrict__ dinv,
                                               const float* __restrict__ bias,
                                               OutT* __restrict__ out, int N) {
    const int NPB = 256 / LPN;
    int d = blockIdx.x * NPB + threadIdx.x / LPN;
    if (d >= N) return;
    int lane = threadIdx.x % LPN;

    float di = dinv[d];
    float w = di * di;
    uint2 raw = *(const uint2*)(xw + (size_t)d * F + lane * 4);
    float2 u0 = __half22float2(*(__half2*)&raw.x);
    float2 u1 = __half22float2(*(__half2*)&raw.y);
    float a0 = w * u0.x, a1 = w * u0.y, a2 = w * u1.x, a3 = w * u1.y;

    int p0 = rowptr[d], p1 = rowptr[d + 1];
    for (int p = p0; p < p1; ++p) {
        int s = col[p];
        float wv = val[p];
        uint2 rv = *(const uint2*)(xw + (size_t)s * F + lane * 4);
        float2 v0 = __half22float2(*(__half2*)&rv.x);
        float2 v1 = __half22float2(*(__half2*)&rv.y);
        a0 = fmaf(wv, v0.x, a0);
        a1 = fmaf(wv, v0.y, a1);
        a2 = fmaf(wv, v1.x, a2);
        a3 = fmaf(wv, v1.y, a3);
    }
    float4 bb = *(const float4*)&bias[lane * 4];
    a0 += bb.x; a1 += bb.y; a2 += bb.z; a3 += bb.w;
    if (RELU) {
        a0 = fmaxf(a0, 0.f); a1 = fmaxf(a1, 0.f);
        a2 = fmaxf(a2, 0.f); a3 = fmaxf(a3, 0.f);
    }
    if constexpr (std::is_same_v<OutT, float>) {
        *(float4*)&out[(size_t)d * F + lane * 4] = make_float4(a0, a1, a2, a3);
    } else {
        __half2 h0 = __floats2half2_rn(a0, a1);
        __half2 h1 = __floats2half2_rn(a2, a3);
        uint2 packed;
        packed.x = *(uint*)&h0;
        packed.y = *(uint*)&h1;
        *(uint2*)&out[(size_t)d * F + lane * 4] = packed;
    }
}

extern "C" void kernel_launch(void* const* d_in, const int* in_sizes, int n_in,
                              void* d_out, int out_size, void* d_ws, size_t ws_size,
                              hipStream_t stream) {
    const float* x  = (const float*)d_in[0];
    const int*   ei = (const int*)d_in[1];
    const float* ew = (const float*)d_in[2];
    const float* W1 = (const float*)d_in[3];
    const float* b1 = (const float*)d_in[4];
    const float* W2 = (const float*)d_in[5];
    const float* b2 = (const float*)d_in[6];
    float* out = (float*)d_out;

    const int H    = in_sizes[4];            // 256
    const int Fout = in_sizes[6];            // 64
    const int Fin  = in_sizes[3] / H;        // 394
    const int N    = in_sizes[0] / Fin;      // 100000
    const int E    = in_sizes[2];            // 1600000

    const int Kpad1 = (Fin + 31) / 32 * 32;  // 416
    const int Kpad2 = (H + 31) / 32 * 32;    // 256

    const int* src = ei;
    const int* dst = ei + E;

    // workspace layout (all sections 16B aligned)
    float* ws     = (float*)d_ws;
    float* dinv   = ws;                           // N
    int*   counts = (int*)(dinv + N);             // N
    int*   fillc  = counts + N;                   // N
    int*   rowptr = fillc + N;                    // N+4
    int*   bsums  = rowptr + N + 4;               // 256
    int*   col    = bsums + 256;                  // E
    float* val    = (float*)(col + E);            // E
    __half* bufA  = (__half*)(val + E);           // N*H (xw1, later xw2)
    __half* bufB  = bufA + (size_t)N * H;         // N*H (h)
    __half* xh    = bufB + (size_t)N * H;         // N*Kpad1
    __half* wt1   = xh + (size_t)N * Kpad1;       // H*Kpad1
    __half* wt2   = wt1 + (size_t)H * Kpad1;      // Fout*Kpad2

    const int NB = (N + SCAN_TILE - 1) / SCAN_TILE;

    // 1. degrees + histogram + dinv
    init_node<<<(N + 255) / 256, 256, 0, stream>>>(dinv, counts, fillc, N);
    accum_deg_hist<<<(E + 255) / 256, 256, 0, stream>>>(dst, ew, dinv, counts, E);
    compute_dinv<<<(N + 255) / 256, 256, 0, stream>>>(dinv, N);

    // 2. CSR build
    scan1<<<NB, 256, 0, stream>>>(counts, rowptr, bsums, N);
    scan2<<<1, 256, 0, stream>>>(bsums, rowptr, NB, N, E);
    scan3<<<NB, 256, 0, stream>>>(rowptr, bsums, N);
    fill_csr<<<(E + 255) / 256, 256, 0, stream>>>(src, dst, ew, dinv, rowptr, fillc, col, val, E);

    // 3. fp16 conversions
    tohalf_w<<<(H * Kpad1 + 255) / 256, 256, 0, stream>>>(W1, wt1, Fin, H, Kpad1);
    tohalf_w<<<(Fout * Kpad2 + 255) / 256, 256, 0, stream>>>(W2, wt2, H, Fout, Kpad2);
    tohalf_x<<<((size_t)N * (Kpad1 / 8) + 255) / 256, 256, 0, stream>>>(x, xh, N, Fin, Kpad1);

    // 4. xw1 = x @ W1   [N,394]@[394,256] -> fp16
    gemm_f16<128, 256, 2, 4, 512><<<(N + 127) / 128, 512, 0, stream>>>(xh, wt1, bufA, N, Kpad1);

    // 5. h = relu(gather + bias) -> fp16
    gatherh<256, 64, 1, __half><<<(N + 3) / 4, 256, 0, stream>>>(
        rowptr, col, val, bufA, dinv, b1, bufB, N);

    // 6. xw2 = h @ W2   [N,256]@[256,64] -> fp16
    gemm_f16<128, 64, 2, 2, 256><<<(N + 127) / 128, 256, 0, stream>>>(bufB, wt2, bufA, N, Kpad2);

    // 7. out = gather + bias -> fp32
    gatherh<64, 16, 0, float><<<(N + 15) / 16, 256, 0, stream>>>(
        rowptr, col, val, bufA, dinv, b2, out, N);
}

// Round 9
// 551.626 us; speedup vs baseline: 13.1612x; 1.1460x over previous
//
#include <hip/hip_runtime.h>
#include <hip/hip_bf16.h>
#include <hip/hip_fp16.h>
#include <type_traits>

// ---------------------------------------------------------------------------
// 2-layer GCN. CSR-gather aggregation (fp16 features, fp32 accum, 4x-unrolled
// edge loop for memory-level parallelism, (col,val) packed as int2).
// GEMMs: fp16 MFMA (fp32 accumulate), global_load_lds double-buffered staging
// with counted vmcnt(3) + raw s_barrier.
// ---------------------------------------------------------------------------

typedef _Float16 f16x8 __attribute__((ext_vector_type(8)));
typedef float f32x4 __attribute__((ext_vector_type(4)));

__device__ inline void async_copy16(const void* g, void* l) {
    __builtin_amdgcn_global_load_lds(
        (const __attribute__((address_space(1))) void*)g,
        (__attribute__((address_space(3))) void*)l, 16, 0, 0);
}

// ------------------------- graph preprocessing -----------------------------

__global__ __launch_bounds__(256) void init_node(float* deg, int* counts, int* fillc, int N) {
    int i = blockIdx.x * 256 + threadIdx.x;
    if (i < N) { deg[i] = 1.0f; counts[i] = 0; fillc[i] = 0; }
}

__global__ __launch_bounds__(256) void accum_deg_hist(const int* __restrict__ dst,
                                                      const float* __restrict__ ew,
                                                      float* deg, int* counts, int E) {
    int e = blockIdx.x * 256 + threadIdx.x;
    if (e < E) {
        int d = dst[e];
        atomicAdd(&deg[d], ew[e]);
        atomicAdd(&counts[d], 1);
    }
}

__global__ __launch_bounds__(256) void compute_dinv(float* deg, int N) {
    int i = blockIdx.x * 256 + threadIdx.x;
    if (i < N) deg[i] = rsqrtf(deg[i]);
}

#define SCAN_TILE 2048

__global__ __launch_bounds__(256) void scan1(const int* __restrict__ counts,
                                             int* __restrict__ rowptr,
                                             int* __restrict__ bsums, int N) {
    __shared__ int tmp[256];
    int t = threadIdx.x;
    int base = blockIdx.x * SCAN_TILE + t * 8;
    int v[8], s = 0;
#pragma unroll
    for (int j = 0; j < 8; ++j) { v[j] = (base + j < N) ? counts[base + j] : 0; s += v[j]; }
    tmp[t] = s;
    __syncthreads();
#pragma unroll
    for (int off = 1; off < 256; off <<= 1) {
        int u = (t >= off) ? tmp[t - off] : 0;
        __syncthreads();
        tmp[t] += u;
        __syncthreads();
    }
    int run = tmp[t] - s;
#pragma unroll
    for (int j = 0; j < 8; ++j) {
        if (base + j < N) rowptr[base + j] = run;
        run += v[j];
    }
    if (t == 255) bsums[blockIdx.x] = tmp[255];
}

__global__ __launch_bounds__(256) void scan2(int* bsums, int* rowptr, int NB, int N, int E) {
    __shared__ int tmp[256];
    int t = threadIdx.x;
    int v = (t < NB) ? bsums[t] : 0;
    tmp[t] = v;
    __syncthreads();
#pragma unroll
    for (int off = 1; off < 256; off <<= 1) {
        int u = (t >= off) ? tmp[t - off] : 0;
        __syncthreads();
        tmp[t] += u;
        __syncthreads();
    }
    if (t < NB) bsums[t] = tmp[t] - v;
    if (t == 0) rowptr[N] = E;
}

__global__ __launch_bounds__(256) void scan3(int* rowptr, const int* __restrict__ bsums, int N) {
    int base = blockIdx.x * SCAN_TILE + threadIdx.x * 8;
    int off = bsums[blockIdx.x];
#pragma unroll
    for (int j = 0; j < 8; ++j)
        if (base + j < N) rowptr[base + j] += off;
}

// (col,val) packed: one 8B scatter per edge instead of two 4B scatters
__global__ __launch_bounds__(256) void fill_csr(const int* __restrict__ src,
                                                const int* __restrict__ dst,
                                                const float* __restrict__ ew,
                                                const float* __restrict__ dinv,
                                                const int* __restrict__ rowptr,
                                                int* __restrict__ fillc,
                                                int2* __restrict__ cv, int E) {
    int e = blockIdx.x * 256 + threadIdx.x;
    if (e < E) {
        int d = dst[e], s = src[e];
        int pos = rowptr[d] + atomicAdd(&fillc[d], 1);
        float v = dinv[s] * ew[e] * dinv[d];
        cv[pos] = make_int2(s, __float_as_int(v));
    }
}

// --------- W[K][N] fp32 -> fp16 transposed [N][Kpad] (zero-padded K) -------
__global__ __launch_bounds__(256) void tohalf_w(const float* __restrict__ W,
                                                __half* __restrict__ WT,
                                                int K, int N, int Kpad) {
    int idx = blockIdx.x * 256 + threadIdx.x;
    int total = N * Kpad;
    if (idx >= total) return;
    int n = idx / Kpad, k = idx % Kpad;
    float v = (k < K) ? W[(size_t)k * N + n] : 0.0f;
    WT[idx] = __float2half(v);
}

// --------- x[N][K] fp32 -> fp16 [N][Kpad] ----------------------------------
__global__ __launch_bounds__(256) void tohalf_x(const float* __restrict__ x,
                                                __half* __restrict__ Xh,
                                                int Nn, int K, int Kpad) {
    int idx = blockIdx.x * 256 + threadIdx.x;  // one 8-elem chunk
    int cpr = Kpad / 8;
    int total = Nn * cpr;
    if (idx >= total) return;
    int row = idx / cpr, c = idx % cpr;
    int gk = c * 8;
    const float* p = x + (size_t)row * K + gk;
    float v[8];
    if (gk + 8 <= K) {
#pragma unroll
        for (int j = 0; j < 4; ++j) {
            float2 t2 = *(const float2*)(p + j * 2);  // 8B-aligned always
            v[j * 2] = t2.x; v[j * 2 + 1] = t2.y;
        }
    } else {
#pragma unroll
        for (int j = 0; j < 8; ++j) v[j] = (gk + j < K) ? p[j] : 0.0f;
    }
    union { __half2 h[4]; uint4 u; } pk;
#pragma unroll
    for (int j = 0; j < 4; ++j) pk.h[j] = __floats2half2_rn(v[j * 2], v[j * 2 + 1]);
    *(uint4*)&Xh[(size_t)row * Kpad + gk] = pk.u;
}

// ---------------- fp16 MFMA GEMM: C[M,BN](fp16) = A[M,Kpad] @ BT^T ---------
template <int BM, int BN, int WARPS_M, int WARPS_N, int NT>
__global__ __launch_bounds__(NT) void gemm_f16(const __half* __restrict__ Ah,
                                               const __half* __restrict__ BT,
                                               __half* __restrict__ C,
                                               int M, int Kpad) {
    const int WM = BM / WARPS_M, WN = BN / WARPS_N;
    const int FM = WM / 16, FN = WN / 16;
    const int ACH = BM * 4;              // 16B chunks for A tile
    const int BCH = BN * 4;              // for B tile
    const int TOTCH = ACH + BCH;
    const int CH = TOTCH / NT;
    static_assert(CH == 3, "vmcnt(3) hardcoded below");
    __shared__ __align__(16) __half lds[2][TOTCH * 8];

    int tid = threadIdx.x;
    int lane = tid & 63;
    int w = tid >> 6;
    int wr = w / WARPS_N, wc = w % WARPS_N;
    int bm = blockIdx.x * BM;
    int lrow = lane & 15;
    int lslot = lane >> 4;

    const __half* srcp[CH];
#pragma unroll
    for (int i = 0; i < CH; ++i) {
        int ch = tid + i * NT;
        if (ch < ACH) {
            int c = ch, row = c >> 2;
            int grow = bm + row;
            if (grow >= M) grow = M - 1;
            srcp[i] = Ah + (size_t)grow * Kpad + (size_t)(((c & 3) ^ ((row >> 1) & 3)) * 8);
        } else {
            int c = ch - ACH, row = c >> 2;
            srcp[i] = BT + (size_t)row * Kpad + (size_t)(((c & 3) ^ ((row >> 1) & 3)) * 8);
        }
    }

    f32x4 acc[FM][FN];
#pragma unroll
    for (int m = 0; m < FM; ++m)
#pragma unroll
        for (int n = 0; n < FN; ++n) acc[m][n] = (f32x4){0.f, 0.f, 0.f, 0.f};

    auto stage = [&](int buf) {
#pragma unroll
        for (int i = 0; i < CH; ++i) {
            async_copy16(srcp[i], &lds[buf][(size_t)((tid & ~63) + i * NT) * 8]);
            srcp[i] += 32;
        }
    };

    auto compute = [&](int buf) {
        f16x8 af[FM], bf[FN];
#pragma unroll
        for (int m = 0; m < FM; ++m) {
            int row = wr * WM + m * 16 + lrow;
            int p = lslot ^ ((row >> 1) & 3);
            af[m] = *(const f16x8*)&lds[buf][(size_t)(row * 4 + p) * 8];
        }
#pragma unroll
        for (int n = 0; n < FN; ++n) {
            int row = wc * WN + n * 16 + lrow;
            int p = lslot ^ ((row >> 1) & 3);
            bf[n] = *(const f16x8*)&lds[buf][(size_t)(ACH + row * 4 + p) * 8];
        }
#pragma unroll
        for (int m = 0; m < FM; ++m)
#pragma unroll
            for (int n = 0; n < FN; ++n)
                acc[m][n] = __builtin_amdgcn_mfma_f32_16x16x32_f16(af[m], bf[n], acc[m][n], 0, 0, 0);
    };

    const int nsteps = Kpad / 32;
    stage(0);
    for (int s = 0; s < nsteps; ++s) {
        if (s + 1 < nsteps) {
            stage((s + 1) & 1);
            asm volatile("s_waitcnt vmcnt(3)" ::: "memory");
        } else {
            asm volatile("s_waitcnt vmcnt(0)" ::: "memory");
        }
        __builtin_amdgcn_s_barrier();
        compute(s & 1);
        __builtin_amdgcn_s_barrier();
    }

#pragma unroll
    for (int m = 0; m < FM; ++m) {
        int rb = bm + wr * WM + m * 16 + (lane >> 4) * 4;
#pragma unroll
        for (int n = 0; n < FN; ++n) {
            int cb = wc * WN + n * 16 + (lane & 15);
#pragma unroll
            for (int i = 0; i < 4; ++i) {
                int r = rb + i;
                if (r < M) C[(size_t)r * BN + cb] = __float2half(acc[m][n][i]);
            }
        }
    }
}

// ---- gather aggregation (fp16 features, fp32 accum, 4x unrolled) ----------
// out[d] = bias + dinv[d]^2*xw[d] + sum_p val[p]*xw[col[p]]  (; relu)
template <int F, int LPN, int RELU, typename OutT>
__global__ __launch_bounds__(256) void gatherh(const int* __restrict__ rowptr,
                                               const int2* __restrict__ cv,
                                               const __half* __restrict__ xw,
                                               const float* __restrict__ dinv,
                                               const float* __restrict__ bias,
                                               OutT* __restrict__ out, int N) {
    const int NPB = 256 / LPN;
    int d = blockIdx.x * NPB + threadIdx.x / LPN;
    if (d >= N) return;
    int lane = threadIdx.x % LPN;

    float di = dinv[d];
    float w = di * di;
    uint2 raw = *(const uint2*)(xw + (size_t)d * F + lane * 4);
    float2 u0 = __half22float2(*(__half2*)&raw.x);
    float2 u1 = __half22float2(*(__half2*)&raw.y);
    float a0 = w * u0.x, a1 = w * u0.y, a2 = w * u1.x, a3 = w * u1.y;
    float b0 = 0.f, b1 = 0.f, b2 = 0.f, b3 = 0.f;  // second accum set

    int p = rowptr[d], p1 = rowptr[d + 1];
    for (; p + 4 <= p1; p += 4) {
        int2 e0 = cv[p], e1 = cv[p + 1], e2 = cv[p + 2], e3 = cv[p + 3];
        uint2 r0 = *(const uint2*)(xw + (size_t)e0.x * F + lane * 4);
        uint2 r1 = *(const uint2*)(xw + (size_t)e1.x * F + lane * 4);
        uint2 r2 = *(const uint2*)(xw + (size_t)e2.x * F + lane * 4);
        uint2 r3 = *(const uint2*)(xw + (size_t)e3.x * F + lane * 4);
        float w0 = __int_as_float(e0.y), w1 = __int_as_float(e1.y);
        float w2 = __int_as_float(e2.y), w3 = __int_as_float(e3.y);
        {
            float2 v0 = __half22float2(*(__half2*)&r0.x);
            float2 v1 = __half22float2(*(__half2*)&r0.y);
            a0 = fmaf(w0, v0.x, a0); a1 = fmaf(w0, v0.y, a1);
            a2 = fmaf(w0, v1.x, a2); a3 = fmaf(w0, v1.y, a3);
        }
        {
            float2 v0 = __half22float2(*(__half2*)&r1.x);
            float2 v1 = __half22float2(*(__half2*)&r1.y);
            b0 = fmaf(w1, v0.x, b0); b1 = fmaf(w1, v0.y, b1);
            b2 = fmaf(w1, v1.x, b2); b3 = fmaf(w1, v1.y, b3);
        }
        {
            float2 v0 = __half22float2(*(__half2*)&r2.x);
            float2 v1 = __half22float2(*(__half2*)&r2.y);
            a0 = fmaf(w2, v0.x, a0); a1 = fmaf(w2, v0.y, a1);
            a2 = fmaf(w2, v1.x, a2); a3 = fmaf(w2, v1.y, a3);
        }
        {
            float2 v0 = __half22float2(*(__half2*)&r3.x);
            float2 v1 = __half22float2(*(__half2*)&r3.y);
            b0 = fmaf(w3, v0.x, b0); b1 = fmaf(w3, v0.y, b1);
            b2 = fmaf(w3, v1.x, b2); b3 = fmaf(w3, v1.y, b3);
        }
    }
    for (; p < p1; ++p) {
        int2 e = cv[p];
        float wv = __int_as_float(e.y);
        uint2 rv = *(const uint2*)(xw + (size_t)e.x * F + lane * 4);
        float2 v0 = __half22float2(*(__half2*)&rv.x);
        float2 v1 = __half22float2(*(__half2*)&rv.y);
        a0 = fmaf(wv, v0.x, a0); a1 = fmaf(wv, v0.y, a1);
        a2 = fmaf(wv, v1.x, a2); a3 = fmaf(wv, v1.y, a3);
    }
    a0 += b0; a1 += b1; a2 += b2; a3 += b3;

    float4 bb = *(const float4*)&bias[lane * 4];
    a0 += bb.x; a1 += bb.y; a2 += bb.z; a3 += bb.w;
    if (RELU) {
        a0 = fmaxf(a0, 0.f); a1 = fmaxf(a1, 0.f);
        a2 = fmaxf(a2, 0.f); a3 = fmaxf(a3, 0.f);
    }
    if constexpr (std::is_same_v<OutT, float>) {
        *(float4*)&out[(size_t)d * F + lane * 4] = make_float4(a0, a1, a2, a3);
    } else {
        __half2 h0 = __floats2half2_rn(a0, a1);
        __half2 h1 = __floats2half2_rn(a2, a3);
        uint2 packed;
        packed.x = *(uint*)&h0;
        packed.y = *(uint*)&h1;
        *(uint2*)&out[(size_t)d * F + lane * 4] = packed;
    }
}

extern "C" void kernel_launch(void* const* d_in, const int* in_sizes, int n_in,
                              void* d_out, int out_size, void* d_ws, size_t ws_size,
                              hipStream_t stream) {
    const float* x  = (const float*)d_in[0];
    const int*   ei = (const int*)d_in[1];
    const float* ew = (const float*)d_in[2];
    const float* W1 = (const float*)d_in[3];
    const float* b1 = (const float*)d_in[4];
    const float* W2 = (const float*)d_in[5];
    const float* b2 = (const float*)d_in[6];
    float* out = (float*)d_out;

    const int H    = in_sizes[4];            // 256
    const int Fout = in_sizes[6];            // 64
    const int Fin  = in_sizes[3] / H;        // 394
    const int N    = in_sizes[0] / Fin;      // 100000
    const int E    = in_sizes[2];            // 1600000

    const int Kpad1 = (Fin + 31) / 32 * 32;  // 416
    const int Kpad2 = (H + 31) / 32 * 32;    // 256

    const int* src = ei;
    const int* dst = ei + E;

    // workspace layout (all sections 16B aligned)
    float* ws     = (float*)d_ws;
    float* dinv   = ws;                           // N
    int*   counts = (int*)(dinv + N);             // N
    int*   fillc  = counts + N;                   // N
    int*   rowptr = fillc + N;                    // N+4
    int*   bsums  = rowptr + N + 4;               // 256
    int2*  cv     = (int2*)(bsums + 256);         // E int2 (col,val)
    __half* bufA  = (__half*)(cv + E);            // N*H (xw1, later xw2)
    __half* bufB  = bufA + (size_t)N * H;         // N*H (h)
    __half* xh    = bufB + (size_t)N * H;         // N*Kpad1
    __half* wt1   = xh + (size_t)N * Kpad1;       // H*Kpad1
    __half* wt2   = wt1 + (size_t)H * Kpad1;      // Fout*Kpad2

    const int NB = (N + SCAN_TILE - 1) / SCAN_TILE;

    // 1. degrees + histogram + dinv
    init_node<<<(N + 255) / 256, 256, 0, stream>>>(dinv, counts, fillc, N);
    accum_deg_hist<<<(E + 255) / 256, 256, 0, stream>>>(dst, ew, dinv, counts, E);
    compute_dinv<<<(N + 255) / 256, 256, 0, stream>>>(dinv, N);

    // 2. CSR build
    scan1<<<NB, 256, 0, stream>>>(counts, rowptr, bsums, N);
    scan2<<<1, 256, 0, stream>>>(bsums, rowptr, NB, N, E);
    scan3<<<NB, 256, 0, stream>>>(rowptr, bsums, N);
    fill_csr<<<(E + 255) / 256, 256, 0, stream>>>(src, dst, ew, dinv, rowptr, fillc, cv, E);

    // 3. fp16 conversions
    tohalf_w<<<(H * Kpad1 + 255) / 256, 256, 0, stream>>>(W1, wt1, Fin, H, Kpad1);
    tohalf_w<<<(Fout * Kpad2 + 255) / 256, 256, 0, stream>>>(W2, wt2, H, Fout, Kpad2);
    tohalf_x<<<((size_t)N * (Kpad1 / 8) + 255) / 256, 256, 0, stream>>>(x, xh, N, Fin, Kpad1);

    // 4. xw1 = x @ W1   [N,394]@[394,256] -> fp16
    gemm_f16<128, 256, 2, 4, 512><<<(N + 127) / 128, 512, 0, stream>>>(xh, wt1, bufA, N, Kpad1);

    // 5. h = relu(gather + bias) -> fp16
    gatherh<256, 64, 1, __half><<<(N + 3) / 4, 256, 0, stream>>>(
        rowptr, cv, bufA, dinv, b1, bufB, N);

    // 6. xw2 = h @ W2   [N,256]@[256,64] -> fp16
    gemm_f16<128, 64, 2, 2, 256><<<(N + 127) / 128, 256, 0, stream>>>(bufB, wt2, bufA, N, Kpad2);

    // 7. out = gather + bias -> fp32
    gatherh<64, 16, 0, float><<<(N + 15) / 16, 256, 0, stream>>>(
        rowptr, cv, bufA, dinv, b2, out, N);
}